// Round 13
// baseline (1327.536 us; speedup 1.0000x reference)
//
#include <hip/hip_runtime.h>
#include <math.h>

#define D 512
#define NH 8
#define DH 64
#define NL 6
#define Bsz 4
#define Lseq 1024
#define BL 4096          // B*L tokens
#define Vocab 30000
#define EPS 1e-5f

typedef __attribute__((ext_vector_type(8))) short s8v;   // 8 bf16 (4 VGPRs)
typedef __attribute__((ext_vector_type(4))) float f32x4; // MFMA accumulator
typedef __attribute__((ext_vector_type(4))) float f4v;   // clang vector (NT-store OK)

__device__ __forceinline__ float sigmoidf_(float x) { return 1.0f / (1.0f + expf(-x)); }

__device__ __forceinline__ short f2bf(float f) {  // fp32 -> bf16 bits, RNE
  union { float f; unsigned u; } v; v.f = f;
  return (short)((v.u + 0x7FFFu + ((v.u >> 16) & 1u)) >> 16);
}
__device__ __forceinline__ float bf2f(short s) {
  union { unsigned u; float f; } v; v.u = ((unsigned)(unsigned short)s) << 16;
  return v.f;
}

// async global->LDS, 16B per lane. LDS dest is wave-uniform base; HW adds lane*16.
__device__ __forceinline__ void gload16(const void* g, void* l) {
  __builtin_amdgcn_global_load_lds(
      (const __attribute__((address_space(1))) void*)g,
      (__attribute__((address_space(3))) void*)l, 16, 0, 0);
}

__device__ __forceinline__ float act_apply(float v, int act) {
  if (act == 1) return 0.5f * v * (1.0f + erff(v * 0.7071067811865475f));
  if (act == 2) return tanhf(v);
  return v;
}

// ---------------- fp32 -> bf16 bulk convert: 6 segments in one launch ----------------
__global__ void f2bf6_kernel(
    const float* __restrict__ s0, short* __restrict__ d0, int n0,
    const float* __restrict__ s1, short* __restrict__ d1, int n1,
    const float* __restrict__ s2, short* __restrict__ d2, int n2,
    const float* __restrict__ s3, short* __restrict__ d3, int n3,
    const float* __restrict__ s4, short* __restrict__ d4, int n4,
    const float* __restrict__ s5, short* __restrict__ d5, int n5) {
  long i = ((long)blockIdx.x * 256 + threadIdx.x) * 8;
  const float* s; short* d;
  if (i < n0) { s = s0; d = d0; }
  else {
    i -= n0;
    if (i < n1) { s = s1; d = d1; }
    else {
      i -= n1;
      if (i < n2) { s = s2; d = d2; }
      else {
        i -= n2;
        if (i < n3) { s = s3; d = d3; }
        else {
          i -= n3;
          if (i < n4) { s = s4; d = d4; }
          else { i -= n4; if (i >= n5) return; s = s5; d = d5; }
        }
      }
    }
  }
  float4 a = *(const float4*)(s + i);
  float4 b = *(const float4*)(s + i + 4);
  s8v o;
  o[0] = f2bf(a.x); o[1] = f2bf(a.y); o[2] = f2bf(a.z); o[3] = f2bf(a.w);
  o[4] = f2bf(b.x); o[5] = f2bf(b.y); o[6] = f2bf(b.z); o[7] = f2bf(b.w);
  *(s8v*)(d + i) = o;
}

// ---------------- embed + pos ----------------
__global__ void embed_kernel(const int* __restrict__ ids, const float* __restrict__ emb,
                             const float* __restrict__ pos, float* __restrict__ x) {
  int tok = blockIdx.x;
  int l = tok & (Lseq - 1);
  int id = ids[tok];
  const float4* e = (const float4*)(emb + (size_t)id * D);
  const float4* p = (const float4*)(pos + (size_t)l * D);
  float4* o = (float4*)(x + (size_t)tok * D);
  float4 a = e[threadIdx.x], b = p[threadIdx.x];
  o[threadIdx.x] = make_float4(a.x + b.x, a.y + b.y, a.z + b.z, a.w + b.w);
}

// ---------- fused rg gate + modulate + layernorm -> bf16 h, + phase (h.pw^T) ----------
__global__ __launch_bounds__(256) void rg_ln_kernel(
    const float* __restrict__ x, const float* __restrict__ rgw, const float* __restrict__ rgb,
    const float* __restrict__ sc, const float* __restrict__ bi,
    const float* __restrict__ pw, const float* __restrict__ pb,
    short* __restrict__ h, float* __restrict__ phase, float* __restrict__ rg_out) {
  __shared__ float smg[4][4];
  __shared__ float sms[4][2];
  __shared__ float smp[4][8];
  int tok = blockIdx.x, t = threadIdx.x, wid = t >> 6, lane = t & 63;
  const float* xr = x + (size_t)tok * D;
  float x0 = xr[t], x1 = xr[t + 256];
  float p0 = x0 * rgw[t]        + x1 * rgw[t + 256];
  float p1 = x0 * rgw[512 + t]  + x1 * rgw[512 + t + 256];
  float p2 = x0 * rgw[1024 + t] + x1 * rgw[1024 + t + 256];
  float p3 = x0 * rgw[1536 + t] + x1 * rgw[1536 + t + 256];
#pragma unroll
  for (int off = 32; off > 0; off >>= 1) {
    p0 += __shfl_xor(p0, off, 64);
    p1 += __shfl_xor(p1, off, 64);
    p2 += __shfl_xor(p2, off, 64);
    p3 += __shfl_xor(p3, off, 64);
  }
  if (lane == 0) { smg[wid][0] = p0; smg[wid][1] = p1; smg[wid][2] = p2; smg[wid][3] = p3; }
  __syncthreads();
  float g0 = sigmoidf_(smg[0][0] + smg[1][0] + smg[2][0] + smg[3][0] + rgb[0]);
  float g1 = sigmoidf_(smg[0][1] + smg[1][1] + smg[2][1] + smg[3][1] + rgb[1]);
  float g2 = sigmoidf_(smg[0][2] + smg[1][2] + smg[2][2] + smg[3][2] + rgb[2]);
  float g3 = sigmoidf_(smg[0][3] + smg[1][3] + smg[2][3] + smg[3][3] + rgb[3]);
  if (rg_out != nullptr && t == 0) {
    float* ro = rg_out + (size_t)tok * 4;
    ro[0] = g0; ro[1] = g1; ro[2] = g2; ro[3] = g3;
  }
  float mod = 1.0f + 0.25f * (g0 + g1 + g2 + g3);
  float m0 = x0 * mod, m1 = x1 * mod;
  float s = m0 + m1, q = m0 * m0 + m1 * m1;
#pragma unroll
  for (int off = 32; off > 0; off >>= 1) {
    s += __shfl_xor(s, off, 64);
    q += __shfl_xor(q, off, 64);
  }
  if (lane == 0) { sms[wid][0] = s; sms[wid][1] = q; }
  __syncthreads();
  float S = sms[0][0] + sms[1][0] + sms[2][0] + sms[3][0];
  float Q = sms[0][1] + sms[1][1] + sms[2][1] + sms[3][1];
  float mean = S * (1.0f / D);
  float var = Q * (1.0f / D) - mean * mean;
  float rstd = rsqrtf(var + EPS);
  float o0 = (m0 - mean) * rstd * sc[t] + bi[t];
  float o1 = (m1 - mean) * rstd * sc[t + 256] + bi[t + 256];
  h[(size_t)tok * D + t] = f2bf(o0);
  h[(size_t)tok * D + t + 256] = f2bf(o1);
  float ph[8];
#pragma unroll
  for (int hh = 0; hh < 8; hh++) {
    ph[hh] = o0 * pw[hh * D + t] + o1 * pw[hh * D + t + 256];
#pragma unroll
    for (int off = 32; off > 0; off >>= 1) ph[hh] += __shfl_xor(ph[hh], off, 64);
  }
  if (lane == 0) {
#pragma unroll
    for (int hh = 0; hh < 8; hh++) smp[wid][hh] = ph[hh];
  }
  __syncthreads();
  if (t < 8)
    phase[(size_t)tok * NH + t] = smp[0][t] + smp[1][t] + smp[2][t] + smp[3][t] + pb[t];
}

// ---------------- residual + layernorm (x fp32 in-place; y is bf16) ----------------
__global__ __launch_bounds__(256) void residual_ln_kernel(
    float* __restrict__ x, const short* __restrict__ y,
    const float* __restrict__ sc, const float* __restrict__ bi,
    short* __restrict__ xb) {
  __shared__ float sms[4][2];
  int tok = blockIdx.x, t = threadIdx.x, wid = t >> 6, lane = t & 63;
  float v0 = x[(size_t)tok * D + t] + bf2f(y[(size_t)tok * D + t]);
  float v1 = x[(size_t)tok * D + t + 256] + bf2f(y[(size_t)tok * D + t + 256]);
  float s = v0 + v1, q = v0 * v0 + v1 * v1;
#pragma unroll
  for (int off = 32; off > 0; off >>= 1) {
    s += __shfl_xor(s, off, 64);
    q += __shfl_xor(q, off, 64);
  }
  if (lane == 0) { sms[wid][0] = s; sms[wid][1] = q; }
  __syncthreads();
  float S = sms[0][0] + sms[1][0] + sms[2][0] + sms[3][0];
  float Q = sms[0][1] + sms[1][1] + sms[2][1] + sms[3][1];
  float mean = S * (1.0f / D);
  float var = Q * (1.0f / D) - mean * mean;
  float rstd = rsqrtf(var + EPS);
  float o0 = (v0 - mean) * rstd * sc[t] + bi[t];
  float o1 = (v1 - mean) * rstd * sc[t + 256] + bi[t + 256];
  x[(size_t)tok * D + t] = o0;
  x[(size_t)tok * D + t + 256] = o1;
  xb[(size_t)tok * D + t] = f2bf(o0);
  xb[(size_t)tok * D + t + 256] = f2bf(o1);
}

// ================= 2-phase dbuf GEMM, BM=128 =================
// MODE 0: fp32 plain  1: fp32 NT (coalesced via LDS)  2: bf16 coalesced (N%128==0)
// MODE 3: qkv — bf16 coalesced for bn<1024 tiles, Vt transposed scatter for bn>=1024.
// SWAP: blockIdx.x = M-tile (bm fastest; W-strip shared across concurrent blocks).
template <int MODE, bool SWAP>
__global__ __launch_bounds__(256) void gemm128_kernel(
    const short* __restrict__ A, const short* __restrict__ W,
    const float* __restrict__ bias, float* __restrict__ C, short* __restrict__ Cb,
    short* __restrict__ Vt, int M, int N, int K, int act) {
  __shared__ char smem[32768];
  short* AsF = (short*)smem;            // [2][128][32] bf16 = 16 KB
  short* WsF = (short*)(smem + 16384);  // [2][128][32] bf16 = 16 KB
  int tid = threadIdx.x;
  int bn, bm;
  if (SWAP) { bm = blockIdx.x * 128; bn = blockIdx.y * 128; }
  else      { bn = blockIdx.x * 128; bm = blockIdx.y * 128; }
  int wid = tid >> 6, lane = tid & 63;
  int wm = (wid >> 1) * 64, wn = (wid & 1) * 64;
  int fr = lane & 15, kg = lane >> 4;
  f32x4 acc[4][4] = {};
  int srow = 32 * wid + (lane >> 2);
  int scol = (lane & 3) * 8;
  const short* Ag0 = A + (size_t)(bm + srow) * K + scol;
  const short* Ag1 = Ag0 + (size_t)16 * K;
  int wr0 = bn + srow;       if (wr0 >= N) wr0 = N - 1;
  int wr1 = bn + srow + 16;  if (wr1 >= N) wr1 = N - 1;
  const short* Wg0 = W + (size_t)wr0 * K + scol;
  const short* Wg1 = W + (size_t)wr1 * K + scol;
  auto stage = [&](int buf, int k0) {
    gload16(Ag0 + k0, AsF + buf * 4096 + (32 * wid) * 32);
    gload16(Ag1 + k0, AsF + buf * 4096 + (32 * wid + 16) * 32);
    gload16(Wg0 + k0, WsF + buf * 4096 + (32 * wid) * 32);
    gload16(Wg1 + k0, WsF + buf * 4096 + (32 * wid + 16) * 32);
  };
  stage(0, 0);
  __syncthreads();
  int nt = K / 32, cur = 0;
  for (int t = 0; t < nt; ++t) {
    if (t + 1 < nt) stage(cur ^ 1, (t + 1) * 32);
    const short* ab = AsF + cur * 4096;
    const short* wb = WsF + cur * 4096;
    s8v af[4], bfv[4];
#pragma unroll
    for (int m = 0; m < 4; m++) af[m] = *(const s8v*)(ab + (wm + m * 16 + fr) * 32 + kg * 8);
#pragma unroll
    for (int n = 0; n < 4; n++) bfv[n] = *(const s8v*)(wb + (wn + n * 16 + fr) * 32 + kg * 8);
#pragma unroll
    for (int m = 0; m < 4; m++)
#pragma unroll
      for (int n = 0; n < 4; n++)
        acc[m][n] = __builtin_amdgcn_mfma_f32_16x16x32_bf16(af[m], bfv[n], acc[m][n], 0, 0, 0);
    __syncthreads();   // drains vmcnt (next tile) + lgkm (this tile's reads)
    cur ^= 1;
  }
  if (MODE == 3 && bn >= 1024) {
    // pure-V tile: transposed scatter to Vt[B][H][DH][L], packed short4 along L
    int rbase = bm + wm + kg * 4;
#pragma unroll
    for (int n = 0; n < 4; n++) {
      int col = bn + wn + n * 16 + fr;
      float bv = bias ? bias[col] : 0.0f;
      int hh = (col - 1024) >> 6, dd = (col - 1024) & 63;
#pragma unroll
      for (int m = 0; m < 4; m++) {
        int row0 = rbase + m * 16;        // multiple of 4
        int bb = row0 >> 10, ll = row0 & 1023;
        short4 pk;
        pk.x = f2bf(acc[m][n][0] + bv);
        pk.y = f2bf(acc[m][n][1] + bv);
        pk.z = f2bf(acc[m][n][2] + bv);
        pk.w = f2bf(acc[m][n][3] + bv);
        *(short4*)&Vt[((((size_t)bb * NH + hh) * DH + dd) << 10) | ll] = pk;
      }
    }
    return;
  }
  if (MODE == 2 || MODE == 3) {
    // ---- LDS-staged coalesced bf16 epilogue: 128 x 128 bf16 = 32 KB ----
    short* eph = (short*)smem;
#pragma unroll
    for (int n = 0; n < 4; n++) {
      int col = wn + n * 16 + fr;
      float bv = bias ? bias[bn + col] : 0.0f;
#pragma unroll
      for (int m = 0; m < 4; m++)
#pragma unroll
        for (int r = 0; r < 4; r++)
          eph[(wm + m * 16 + kg * 4 + r) * 128 + col] = f2bf(act_apply(acc[m][n][r] + bv, act));
    }
    __syncthreads();
#pragma unroll
    for (int i = 0; i < 8; i++) {
      int idx = tid + i * 256;          // 0..2047
      int rl = idx >> 4;                // 0..127
      int c8 = (idx & 15) * 8;          // 0..120
      *(s8v*)&Cb[(size_t)(bm + rl) * N + bn + c8] = *(s8v*)&eph[rl * 128 + c8];
    }
    return;
  }
  // ---- fp32 epilogue: 2 chunks of 64 rows x 128 cols through LDS, coalesced (NT) ----
  float* eps = (float*)smem;   // 64*128*4 = 32 KB
#pragma unroll
  for (int c = 0; c < 2; ++c) {
    __syncthreads();
    if ((wid >> 1) == c) {
#pragma unroll
      for (int n = 0; n < 4; n++) {
        int col = wn + n * 16 + fr;
        int gcol = bn + col;
        float bv = bias ? bias[gcol < N ? gcol : N - 1] : 0.0f;
#pragma unroll
        for (int m = 0; m < 4; m++)
#pragma unroll
          for (int r = 0; r < 4; r++)
            eps[(m * 16 + kg * 4 + r) * 128 + col] = act_apply(acc[m][n][r] + bv, act);
      }
    }
    __syncthreads();
#pragma unroll
    for (int i = 0; i < 8; i++) {
      int idx = tid + i * 256;          // 0..2047
      int rl = idx >> 5;                // 0..63
      int c4 = (idx & 31) * 4;          // 0..124
      int row = bm + c * 64 + rl;
      int col = bn + c4;
      f4v v = *(f4v*)&eps[rl * 128 + c4];
      float* dst = C + (size_t)row * N + col;
      if (col + 3 < N) {
        if (MODE == 1) __builtin_nontemporal_store(v, (f4v*)dst);
        else *(f4v*)dst = v;
      } else {
        for (int j = 0; j < 4; j++)
          if (col + j < N) {
            if (MODE == 1) __builtin_nontemporal_store(v[j], dst + j);
            else dst[j] = v[j];
          }
      }
    }
  }
}

// ================= 2-phase dbuf GEMM, BM=64 =================
// OUTBF: LDS-staged coalesced bf16 epilogue (requires N % 128 == 0).
template <bool OUTBF>
__global__ __launch_bounds__(256) void gemm64_kernel(
    const short* __restrict__ A, const short* __restrict__ W,
    const float* __restrict__ bias, float* __restrict__ C, short* __restrict__ Cb,
    short* __restrict__ Vt, int M, int N, int K, int act) {
  __shared__ char smem[24576];
  short* AsF = (short*)smem;            // [2][64][32] = 8 KB
  short* WsF = (short*)(smem + 8192);   // [2][128][32] = 16 KB
  int tid = threadIdx.x;
  int bn = blockIdx.x * 128, bm = blockIdx.y * 64;
  int wid = tid >> 6, lane = tid & 63;
  int fr = lane & 15, kg = lane >> 4;
  f32x4 acc[4][2] = {};
  int l4 = lane >> 2;
  int scol = (lane & 3) * 8;
  const short* Ag0 = A + (size_t)(bm + 16 * wid + l4) * K + scol;
  int wr0 = bn + 32 * wid + l4;       if (wr0 >= N) wr0 = N - 1;
  int wr1 = bn + 32 * wid + 16 + l4;  if (wr1 >= N) wr1 = N - 1;
  const short* Wg0 = W + (size_t)wr0 * K + scol;
  const short* Wg1 = W + (size_t)wr1 * K + scol;
  auto stage = [&](int buf, int k0) {
    gload16(Ag0 + k0, AsF + buf * 2048 + (16 * wid) * 32);
    gload16(Wg0 + k0, WsF + buf * 4096 + (32 * wid) * 32);
    gload16(Wg1 + k0, WsF + buf * 4096 + (32 * wid + 16) * 32);
  };
  stage(0, 0);
  __syncthreads();
  int nt = K / 32, cur = 0;
  for (int t = 0; t < nt; ++t) {
    if (t + 1 < nt) stage(cur ^ 1, (t + 1) * 32);
    const short* ab = AsF + cur * 2048;
    const short* wb = WsF + cur * 4096;
    s8v af[4], bfv[2];
#pragma unroll
    for (int m = 0; m < 4; m++) af[m] = *(const s8v*)(ab + (m * 16 + fr) * 32 + kg * 8);
#pragma unroll
    for (int n = 0; n < 2; n++) bfv[n] = *(const s8v*)(wb + (wid * 32 + n * 16 + fr) * 32 + kg * 8);
#pragma unroll
    for (int m = 0; m < 4; m++)
#pragma unroll
      for (int n = 0; n < 2; n++)
        acc[m][n] = __builtin_amdgcn_mfma_f32_16x16x32_bf16(af[m], bfv[n], acc[m][n], 0, 0, 0);
    __syncthreads();
    cur ^= 1;
  }
  int rbase = bm + kg * 4;
  if (OUTBF) {
    // ---- LDS-staged coalesced bf16 epilogue: 64 rows x 128 cols = 16 KB ----
    short* eph = (short*)smem;
    __syncthreads();
#pragma unroll
    for (int n = 0; n < 2; n++) {
      int col = wid * 32 + n * 16 + fr;
      float bv = bias ? bias[bn + col] : 0.0f;
#pragma unroll
      for (int m = 0; m < 4; m++)
#pragma unroll
        for (int r = 0; r < 4; r++)
          eph[(kg * 4 + m * 16 + r) * 128 + col] = f2bf(act_apply(acc[m][n][r] + bv, act));
    }
    __syncthreads();
#pragma unroll
    for (int i = 0; i < 4; i++) {
      int idx = tid + i * 256;          // 0..1023
      int rl = idx >> 4;                // 0..63
      int c8 = (idx & 15) * 8;          // 0..120
      *(s8v*)&Cb[(size_t)(bm + rl) * N + bn + c8] = *(s8v*)&eph[rl * 128 + c8];
    }
  } else {
#pragma unroll
    for (int n = 0; n < 2; n++) {
      int col = bn + wid * 32 + n * 16 + fr;
      if (col >= N) continue;
      float bv = bias ? bias[col] : 0.0f;
#pragma unroll
      for (int m = 0; m < 4; m++)
#pragma unroll
        for (int r = 0; r < 4; r++)
          C[(size_t)(rbase + m * 16 + r) * N + col] = act_apply(acc[m][n][r] + bv, act);
    }
  }
}

// ---------------- fallback GEMM (fp32 weights converted in staging) ----------------
template <bool OUTBF>
__global__ __launch_bounds__(256) void gemm_conv_kernel(
    const short* __restrict__ A, const float* __restrict__ Wp,
    const float* __restrict__ bias, float* __restrict__ C, short* __restrict__ Cb,
    short* __restrict__ Vt, int M, int N, int K, int act) {
  __shared__ short As[128][40];
  __shared__ short Ws[128][40];
  int tid = threadIdx.x;
  int bn = blockIdx.x * 128, bm = blockIdx.y * 128;
  int wid = tid >> 6, lane = tid & 63;
  int wm = (wid >> 1) * 64, wn = (wid & 1) * 64;
  int fr = lane & 15, kg = lane >> 4;
  f32x4 acc[4][4] = {};
  int sr = tid >> 1;
  int sc = (tid & 1) * 16;
  const short* Arow = A + (size_t)(bm + sr) * K + sc;
  int wrow = bn + sr;
  int wclamp = wrow < N ? wrow : 0;
  const float* Wrow_f = Wp + (size_t)wclamp * K + sc;
  for (int k0 = 0; k0 < K; k0 += 32) {
    s8v a0 = *(const s8v*)(Arow + k0);
    s8v a1 = *(const s8v*)(Arow + k0 + 8);
    s8v w0, w1;
    float4 f0 = *(const float4*)(Wrow_f + k0);
    float4 f1 = *(const float4*)(Wrow_f + k0 + 4);
    float4 f2 = *(const float4*)(Wrow_f + k0 + 8);
    float4 f3 = *(const float4*)(Wrow_f + k0 + 12);
    w0[0] = f2bf(f0.x); w0[1] = f2bf(f0.y); w0[2] = f2bf(f0.z); w0[3] = f2bf(f0.w);
    w0[4] = f2bf(f1.x); w0[5] = f2bf(f1.y); w0[6] = f2bf(f1.z); w0[7] = f2bf(f1.w);
    w1[0] = f2bf(f2.x); w1[1] = f2bf(f2.y); w1[2] = f2bf(f2.z); w1[3] = f2bf(f2.w);
    w1[4] = f2bf(f3.x); w1[5] = f2bf(f3.y); w1[6] = f2bf(f3.z); w1[7] = f2bf(f3.w);
    __syncthreads();
    *(s8v*)&As[sr][sc] = a0;
    *(s8v*)&As[sr][sc + 8] = a1;
    *(s8v*)&Ws[sr][sc] = w0;
    *(s8v*)&Ws[sr][sc + 8] = w1;
    __syncthreads();
    s8v af[4], bfv[4];
#pragma unroll
    for (int m = 0; m < 4; m++) af[m] = *(const s8v*)&As[wm + m * 16 + fr][kg * 8];
#pragma unroll
    for (int n = 0; n < 4; n++) bfv[n] = *(const s8v*)&Ws[wn + n * 16 + fr][kg * 8];
#pragma unroll
    for (int m = 0; m < 4; m++)
#pragma unroll
      for (int n = 0; n < 4; n++)
        acc[m][n] = __builtin_amdgcn_mfma_f32_16x16x32_bf16(af[m], bfv[n], acc[m][n], 0, 0, 0);
  }
  int rbase = bm + wm + kg * 4;
#pragma unroll
  for (int n = 0; n < 4; n++) {
    int col = bn + wn + n * 16 + fr;
    if (col >= N) continue;
    float bv = bias ? bias[col] : 0.0f;
    if (Vt != nullptr && col >= 1024) {
      int hh = (col - 1024) >> 6, dd = (col - 1024) & 63;
#pragma unroll
      for (int m = 0; m < 4; m++) {
        int row0 = rbase + m * 16;
        int bb = row0 >> 10, ll = row0 & 1023;
        short4 pk;
        pk.x = f2bf(acc[m][n][0] + bv);
        pk.y = f2bf(acc[m][n][1] + bv);
        pk.z = f2bf(acc[m][n][2] + bv);
        pk.w = f2bf(acc[m][n][3] + bv);
        *(short4*)&Vt[((((size_t)bb * NH + hh) * DH + dd) << 10) | ll] = pk;
      }
      continue;
    }
#pragma unroll
    for (int m = 0; m < 4; m++) {
#pragma unroll
      for (int r = 0; r < 4; r++) {
        int row = rbase + m * 16 + r;
        float v = act_apply(acc[m][n][r] + bv, act);
        if (OUTBF) Cb[(size_t)row * N + col] = f2bf(v);
        else C[(size_t)row * N + col] = v;
      }
    }
  }
}

// ---------------- MFMA flash attention (V pre-transposed) ----------------
__global__ __launch_bounds__(256) void mha_kernel(
    const short* __restrict__ qkv, const short* __restrict__ vt,
    const float* __restrict__ phase, short* __restrict__ out) {
  __shared__ short sQ[64][72];
  __shared__ short sK[64][72];
  __shared__ short sVt[64][72];
  __shared__ short sP[64][72];
  __shared__ float sPh[Lseq];
  int bh = blockIdx.y;
  int b = bh >> 3, h = bh & 7;
  int q0 = blockIdx.x * 64;
  int tid = threadIdx.x;
  int lane = tid & 63, wid = tid >> 6;
  int fr = lane & 15, kg = lane >> 4;
  int wm = wid * 16;
  const short* vtb = vt + ((size_t)bh * DH) * Lseq;

  for (int j = tid; j < Lseq; j += 256) sPh[j] = phase[((size_t)(b * Lseq + j)) * NH + h];
  for (int idx = tid; idx < 512; idx += 256) {
    int row = idx >> 3, c8 = (idx & 7) * 8;
    *(s8v*)&sQ[row][c8] =
        *(const s8v*)(qkv + (((size_t)(b * Lseq + q0 + row)) * 3 + 0) * D + h * DH + c8);
  }
  __syncthreads();

  float phq[4];
#pragma unroll
  for (int r = 0; r < 4; r++) phq[r] = sPh[q0 + wm + kg * 4 + r];

  float mrow[4] = {-1e30f, -1e30f, -1e30f, -1e30f};
  float lrow[4] = {0.f, 0.f, 0.f, 0.f};
  f32x4 o[4] = {};

  for (int kt = 0; kt < Lseq / 64; kt++) {
    int k0 = kt * 64;
    __syncthreads();
    for (int idx = tid; idx < 512; idx += 256) {
      int row = idx >> 3, c8 = (idx & 7) * 8;
      *(s8v*)&sK[row][c8] =
          *(const s8v*)(qkv + (((size_t)(b * Lseq + k0 + row)) * 3 + 1) * D + h * DH + c8);
      *(s8v*)&sVt[row][c8] = *(const s8v*)(vtb + (size_t)row * Lseq + k0 + c8);
    }
    __syncthreads();

    s8v qa0 = *(const s8v*)&sQ[wm + fr][kg * 8];
    s8v qa1 = *(const s8v*)&sQ[wm + fr][32 + kg * 8];
    f32x4 sacc[4];
#pragma unroll
    for (int n = 0; n < 4; n++) {
      f32x4 z = {};
      s8v kb0 = *(const s8v*)&sK[n * 16 + fr][kg * 8];
      s8v kb1 = *(const s8v*)&sK[n * 16 + fr][32 + kg * 8];
      z = __builtin_amdgcn_mfma_f32_16x16x32_bf16(qa0, kb0, z, 0, 0, 0);
      z = __builtin_amdgcn_mfma_f32_16x16x32_bf16(qa1, kb1, z, 0, 0, 0);
      sacc[n] = z;
    }
    float sv[4][4];
#pragma unroll
    for (int n = 0; n < 4; n++) {
      float phk = sPh[k0 + n * 16 + fr];
#pragma unroll
      for (int r = 0; r < 4; r++) {
        float dp = phq[r] - phk;
        sv[n][r] = sacc[n][r] * 0.125f - dp * dp;
      }
    }
    float mnew[4], alpha[4];
#pragma unroll
    for (int r = 0; r < 4; r++) {
      float mx = fmaxf(fmaxf(sv[0][r], sv[1][r]), fmaxf(sv[2][r], sv[3][r]));
#pragma unroll
      for (int off = 1; off < 16; off <<= 1) mx = fmaxf(mx, __shfl_xor(mx, off, 64));
      mnew[r] = fmaxf(mrow[r], mx);
      alpha[r] = __expf(mrow[r] - mnew[r]);
      mrow[r] = mnew[r];
    }
    float rs[4] = {0.f, 0.f, 0.f, 0.f};
#pragma unroll
    for (int n = 0; n < 4; n++) {
#pragma unroll
      for (int r = 0; r < 4; r++) {
        float p = __expf(sv[n][r] - mnew[r]);
        rs[r] += p;
        sP[wm + kg * 4 + r][n * 16 + fr] = f2bf(p);
      }
    }
#pragma unroll
    for (int r = 0; r < 4; r++) {
#pragma unroll
      for (int off = 1; off < 16; off <<= 1) rs[r] += __shfl_xor(rs[r], off, 64);
      lrow[r] = lrow[r] * alpha[r] + rs[r];
    }
#pragma unroll
    for (int df = 0; df < 4; df++) {
      o[df][0] *= alpha[0]; o[df][1] *= alpha[1];
      o[df][2] *= alpha[2]; o[df][3] *= alpha[3];
    }
    s8v pa0 = *(const s8v*)&sP[wm + fr][kg * 8];
    s8v pa1 = *(const s8v*)&sP[wm + fr][32 + kg * 8];
#pragma unroll
    for (int df = 0; df < 4; df++) {
      int d = df * 16 + fr;
      s8v vb0 = *(const s8v*)&sVt[d][kg * 8];
      s8v vb1 = *(const s8v*)&sVt[d][32 + kg * 8];
      o[df] = __builtin_amdgcn_mfma_f32_16x16x32_bf16(pa0, vb0, o[df], 0, 0, 0);
      o[df] = __builtin_amdgcn_mfma_f32_16x16x32_bf16(pa1, vb1, o[df], 0, 0, 0);
    }
  }
  float inv[4];
#pragma unroll
  for (int r = 0; r < 4; r++) inv[r] = 1.0f / lrow[r];
#pragma unroll
  for (int df = 0; df < 4; df++) {
#pragma unroll
    for (int r = 0; r < 4; r++) {
      int row = q0 + wm + kg * 4 + r;
      out[((size_t)(b * Lseq + row)) * D + h * DH + df * 16 + fr] = f2bf(o[df][r] * inv[r]);
    }
  }
}

// ---------------- boundary gate ----------------
__global__ void gate_kernel(const float* __restrict__ tb, const float* __restrict__ w2,
                            const float* __restrict__ b2, float* __restrict__ gate) {
  int tok = blockIdx.x;
  int lane = threadIdx.x;  // 64
  const float* row = tb + (size_t)tok * D;
  float acc = 0.f;
  for (int d = lane; d < D; d += 64) acc += row[d] * w2[d];
  for (int off = 32; off > 0; off >>= 1) acc += __shfl_down(acc, off, 64);
  if (lane == 0) gate[tok] = 1.0f / (1.0f + expf(-(acc + b2[0])));
}

// ---------------- xg = bf16(x * gate) ----------------
__global__ void xg_kernel(const float* __restrict__ x, const float* __restrict__ gate,
                          short* __restrict__ xg) {
  int tok = blockIdx.x, t = threadIdx.x;
  float g = gate[tok];
  float4 v = *(const float4*)(x + (size_t)tok * D + t * 4);
  short4 o = make_short4(f2bf(v.x * g), f2bf(v.y * g), f2bf(v.z * g), f2bf(v.w * g));
  *(short4*)(xg + (size_t)tok * D + t * 4) = o;
}

extern "C" void kernel_launch(void* const* d_in, const int* in_sizes, int n_in,
                              void* d_out, int out_size, void* d_ws, size_t ws_size,
                              hipStream_t stream) {
  const int* ids = (const int*)d_in[0];
  const float* emb = (const float*)d_in[1];
  const float* pos = (const float*)d_in[2];
  const float* rg_w = (const float*)d_in[3];
  const float* rg_b = (const float*)d_in[4];
  const float* qkv_w = (const float*)d_in[5];
  const float* qkv_b = (const float*)d_in[6];
  const float* out_w = (const float*)d_in[7];
  const float* out_b = (const float*)d_in[8];
  const float* ph_w = (const float*)d_in[9];
  const float* ph_b = (const float*)d_in[10];
  const float* ff1_w = (const float*)d_in[11];
  const float* ff1_b = (const float*)d_in[12];
  const float* ff2_w = (const float*)d_in[13];
  const float* ff2_b = (const float*)d_in[14];
  const float* n1_s = (const float*)d_in[15];
  const float* n1_b = (const float*)d_in[16];
  const float* n2_s = (const float*)d_in[17];
  const float* n2_b = (const float*)d_in[18];
  const float* bw1 = (const float*)d_in[19];
  const float* bb1 = (const float*)d_in[20];
  const float* bw2 = (const float*)d_in[21];
  const float* bb2 = (const float*)d_in[22];
  const float* head_w = (const float*)d_in[23];

  char* w = (char*)d_ws;
  float* x      = (float*)(w + 0);           //  8.39 MB
  float* ao     = (float*)(w + 8388608);     //  8.39 MB (bnd tanh-buf; first 4.2 MB doubles as y_bf)
  short* y_bf   = (short*)(w + 8388608);     //  4.19 MB (residual-add input, bf16)
  float* phase  = (float*)(w + 16777216);    //  0.13 MB
  short* h_bf   = (short*)(w + 16908288);    //  4.19 MB
  short* ao_bf  = (short*)(w + 21102592);    //  4.19 MB
  short* x_bf   = (short*)(w + 25296896);    //  4.19 MB
  short* ff_bf  = (short*)(w + 29491200);    // 16.78 MB
  short* xg_bf  = (short*)(w + 46268416);    //  4.19 MB
  short* qkv_bf = (short*)(w + 50462720);    // 12.58 MB
  short* vt_bf  = (short*)(w + 63045632);    //  4.19 MB
  short* wqkv   = (short*)(w + 67239936);    //  9.44 MB
  short* wout   = (short*)(w + 76677120);    //  3.15 MB
  short* wff1   = (short*)(w + 79822848);    // 12.58 MB
  short* wff2   = (short*)(w + 92405760);    // 12.58 MB
  short* wbnd   = (short*)(w + 104988672);   //  0.52 MB
  short* whead  = (short*)(w + 105512960);   // 30.72 MB
  const size_t WS_FULL = 136232960;

  float* outf   = (float*)d_out;
  float* logits = outf;
  float* gate   = outf + 122880000;
  float* rg_out = outf + 122884096;

  bool fast = ws_size >= WS_FULL;

  if (fast) {
    // one launch for all six weight conversions (34,496,512 elements / 8 per thread)
    f2bf6_kernel<<<(34496512 / 8 + 255) / 256, 256, 0, stream>>>(
        qkv_w, wqkv, 4718592, out_w, wout, 1572864, ff1_w, wff1, 6291456,
        ff2_w, wff2, 6291456, bw1, wbnd, 262144, head_w, whead, 15360000);
  }

  embed_kernel<<<BL, 128, 0, stream>>>(ids, emb, pos, x);

  for (int l = 0; l < NL; l++) {
    rg_ln_kernel<<<BL, 256, 0, stream>>>(
        x, rg_w + (size_t)l * 4 * D, rg_b + l * 4, n1_s + l * D, n1_b + l * D,
        ph_w + (size_t)l * NH * D, ph_b + l * NH,
        h_bf, phase, (l == NL - 1) ? rg_out : nullptr);
    if (fast)
      gemm128_kernel<3, false><<<dim3(12, 32), 256, 0, stream>>>(
          h_bf, wqkv + (size_t)l * 1536 * D, qkv_b + l * 1536, nullptr, qkv_bf, vt_bf,
          BL, 1536, D, 0);
    else
      gemm_conv_kernel<true><<<dim3(12, 32), 256, 0, stream>>>(
          h_bf, qkv_w + (size_t)l * 1536 * D, qkv_b + l * 1536, nullptr, qkv_bf, vt_bf,
          BL, 1536, D, 0);
    mha_kernel<<<dim3(Lseq / 64, Bsz * NH), 256, 0, stream>>>(qkv_bf, vt_bf, phase, ao_bf);
    if (fast)
      gemm64_kernel<true><<<dim3(4, 64), 256, 0, stream>>>(
          ao_bf, wout + (size_t)l * D * D, out_b + l * D, nullptr, y_bf, nullptr, BL, D, D, 0);
    else
      gemm_conv_kernel<true><<<dim3(4, 32), 256, 0, stream>>>(
          ao_bf, out_w + (size_t)l * D * D, out_b + l * D, nullptr, y_bf, nullptr, BL, D, D, 0);
    residual_ln_kernel<<<BL, 256, 0, stream>>>(x, y_bf, n1_s + l * D, n1_b + l * D, x_bf);
    if (fast)
      gemm128_kernel<2, false><<<dim3(16, 32), 256, 0, stream>>>(
          x_bf, wff1 + (size_t)l * 2048 * D, ff1_b + l * 2048, nullptr, ff_bf, nullptr,
          BL, 2048, D, 1);
    else
      gemm_conv_kernel<true><<<dim3(16, 32), 256, 0, stream>>>(
          x_bf, ff1_w + (size_t)l * 2048 * D, ff1_b + l * 2048, nullptr, ff_bf, nullptr,
          BL, 2048, D, 1);
    if (fast)
      gemm64_kernel<true><<<dim3(4, 64), 256, 0, stream>>>(
          ff_bf, wff2 + (size_t)l * D * 2048, ff2_b + l * D, nullptr, y_bf, nullptr,
          BL, D, 2048, 0);
    else
      gemm_conv_kernel<true><<<dim3(4, 32), 256, 0, stream>>>(
          ff_bf, ff2_w + (size_t)l * D * 2048, ff2_b + l * D, nullptr, y_bf, nullptr,
          BL, D, 2048, 0);
    residual_ln_kernel<<<BL, 256, 0, stream>>>(x, y_bf, n2_s + l * D, n2_b + l * D, x_bf);
  }

  if (fast)
    gemm64_kernel<false><<<dim3(4, 64), 256, 0, stream>>>(
        x_bf, wbnd, bb1, ao, nullptr, nullptr, BL, D, D, 2);
  else
    gemm_conv_kernel<false><<<dim3(4, 32), 256, 0, stream>>>(
        x_bf, bw1, bb1, ao, nullptr, nullptr, BL, D, D, 2);
  gate_kernel<<<BL, 64, 0, stream>>>(ao, bw2, bb2, gate);
  xg_kernel<<<BL, 128, 0, stream>>>(x, gate, xg_bf);
  if (fast)
    gemm128_kernel<1, true><<<dim3(32, 235), 256, 0, stream>>>(
        xg_bf, whead, nullptr, logits, nullptr, nullptr, BL, Vocab, D, 0);
  else
    gemm_conv_kernel<false><<<dim3(235, 32), 256, 0, stream>>>(
        xg_bf, head_w, nullptr, logits, nullptr, nullptr, BL, Vocab, D, 0);
}

// Round 14
// 1220.447 us; speedup vs baseline: 1.0877x; 1.0877x over previous
//
#include <hip/hip_runtime.h>
#include <math.h>

#define D 512
#define NH 8
#define DH 64
#define NL 6
#define Bsz 4
#define Lseq 1024
#define BL 4096          // B*L tokens
#define Vocab 30000
#define EPS 1e-5f

typedef __attribute__((ext_vector_type(8))) short s8v;   // 8 bf16 (4 VGPRs)
typedef __attribute__((ext_vector_type(4))) float f32x4; // MFMA accumulator
typedef __attribute__((ext_vector_type(4))) float f4v;   // clang vector (NT-store OK)

__device__ __forceinline__ float sigmoidf_(float x) { return 1.0f / (1.0f + expf(-x)); }

__device__ __forceinline__ short f2bf(float f) {  // fp32 -> bf16 bits, RNE
  union { float f; unsigned u; } v; v.f = f;
  return (short)((v.u + 0x7FFFu + ((v.u >> 16) & 1u)) >> 16);
}
__device__ __forceinline__ float bf2f(short s) {
  union { unsigned u; float f; } v; v.u = ((unsigned)(unsigned short)s) << 16;
  return v.f;
}

// async global->LDS, 16B per lane. LDS dest is wave-uniform base; HW adds lane*16.
__device__ __forceinline__ void gload16(const void* g, void* l) {
  __builtin_amdgcn_global_load_lds(
      (const __attribute__((address_space(1))) void*)g,
      (__attribute__((address_space(3))) void*)l, 16, 0, 0);
}

__device__ __forceinline__ float act_apply(float v, int act) {
  if (act == 1) return 0.5f * v * (1.0f + erff(v * 0.7071067811865475f));
  if (act == 2) return tanhf(v);
  return v;
}

// ---------------- fp32 -> bf16 bulk convert: 6 segments in one launch ----------------
__global__ void f2bf6_kernel(
    const float* __restrict__ s0, short* __restrict__ d0, int n0,
    const float* __restrict__ s1, short* __restrict__ d1, int n1,
    const float* __restrict__ s2, short* __restrict__ d2, int n2,
    const float* __restrict__ s3, short* __restrict__ d3, int n3,
    const float* __restrict__ s4, short* __restrict__ d4, int n4,
    const float* __restrict__ s5, short* __restrict__ d5, int n5) {
  long i = ((long)blockIdx.x * 256 + threadIdx.x) * 8;
  const float* s; short* d;
  if (i < n0) { s = s0; d = d0; }
  else {
    i -= n0;
    if (i < n1) { s = s1; d = d1; }
    else {
      i -= n1;
      if (i < n2) { s = s2; d = d2; }
      else {
        i -= n2;
        if (i < n3) { s = s3; d = d3; }
        else {
          i -= n3;
          if (i < n4) { s = s4; d = d4; }
          else { i -= n4; if (i >= n5) return; s = s5; d = d5; }
        }
      }
    }
  }
  float4 a = *(const float4*)(s + i);
  float4 b = *(const float4*)(s + i + 4);
  s8v o;
  o[0] = f2bf(a.x); o[1] = f2bf(a.y); o[2] = f2bf(a.z); o[3] = f2bf(a.w);
  o[4] = f2bf(b.x); o[5] = f2bf(b.y); o[6] = f2bf(b.z); o[7] = f2bf(b.w);
  *(s8v*)(d + i) = o;
}

// ---------------- embed + pos ----------------
__global__ void embed_kernel(const int* __restrict__ ids, const float* __restrict__ emb,
                             const float* __restrict__ pos, float* __restrict__ x) {
  int tok = blockIdx.x;
  int l = tok & (Lseq - 1);
  int id = ids[tok];
  const float4* e = (const float4*)(emb + (size_t)id * D);
  const float4* p = (const float4*)(pos + (size_t)l * D);
  float4* o = (float4*)(x + (size_t)tok * D);
  float4 a = e[threadIdx.x], b = p[threadIdx.x];
  o[threadIdx.x] = make_float4(a.x + b.x, a.y + b.y, a.z + b.z, a.w + b.w);
}

// ---------- fused rg gate + modulate + layernorm -> bf16 h, + phase (h.pw^T) ----------
__global__ __launch_bounds__(256) void rg_ln_kernel(
    const float* __restrict__ x, const float* __restrict__ rgw, const float* __restrict__ rgb,
    const float* __restrict__ sc, const float* __restrict__ bi,
    const float* __restrict__ pw, const float* __restrict__ pb,
    short* __restrict__ h, float* __restrict__ phase, float* __restrict__ rg_out) {
  __shared__ float smg[4][4];
  __shared__ float sms[4][2];
  __shared__ float smp[4][8];
  int tok = blockIdx.x, t = threadIdx.x, wid = t >> 6, lane = t & 63;
  const float* xr = x + (size_t)tok * D;
  float x0 = xr[t], x1 = xr[t + 256];
  float p0 = x0 * rgw[t]        + x1 * rgw[t + 256];
  float p1 = x0 * rgw[512 + t]  + x1 * rgw[512 + t + 256];
  float p2 = x0 * rgw[1024 + t] + x1 * rgw[1024 + t + 256];
  float p3 = x0 * rgw[1536 + t] + x1 * rgw[1536 + t + 256];
#pragma unroll
  for (int off = 32; off > 0; off >>= 1) {
    p0 += __shfl_xor(p0, off, 64);
    p1 += __shfl_xor(p1, off, 64);
    p2 += __shfl_xor(p2, off, 64);
    p3 += __shfl_xor(p3, off, 64);
  }
  if (lane == 0) { smg[wid][0] = p0; smg[wid][1] = p1; smg[wid][2] = p2; smg[wid][3] = p3; }
  __syncthreads();
  float g0 = sigmoidf_(smg[0][0] + smg[1][0] + smg[2][0] + smg[3][0] + rgb[0]);
  float g1 = sigmoidf_(smg[0][1] + smg[1][1] + smg[2][1] + smg[3][1] + rgb[1]);
  float g2 = sigmoidf_(smg[0][2] + smg[1][2] + smg[2][2] + smg[3][2] + rgb[2]);
  float g3 = sigmoidf_(smg[0][3] + smg[1][3] + smg[2][3] + smg[3][3] + rgb[3]);
  if (rg_out != nullptr && t == 0) {
    float* ro = rg_out + (size_t)tok * 4;
    ro[0] = g0; ro[1] = g1; ro[2] = g2; ro[3] = g3;
  }
  float mod = 1.0f + 0.25f * (g0 + g1 + g2 + g3);
  float m0 = x0 * mod, m1 = x1 * mod;
  float s = m0 + m1, q = m0 * m0 + m1 * m1;
#pragma unroll
  for (int off = 32; off > 0; off >>= 1) {
    s += __shfl_xor(s, off, 64);
    q += __shfl_xor(q, off, 64);
  }
  if (lane == 0) { sms[wid][0] = s; sms[wid][1] = q; }
  __syncthreads();
  float S = sms[0][0] + sms[1][0] + sms[2][0] + sms[3][0];
  float Q = sms[0][1] + sms[1][1] + sms[2][1] + sms[3][1];
  float mean = S * (1.0f / D);
  float var = Q * (1.0f / D) - mean * mean;
  float rstd = rsqrtf(var + EPS);
  float o0 = (m0 - mean) * rstd * sc[t] + bi[t];
  float o1 = (m1 - mean) * rstd * sc[t + 256] + bi[t + 256];
  h[(size_t)tok * D + t] = f2bf(o0);
  h[(size_t)tok * D + t + 256] = f2bf(o1);
  float ph[8];
#pragma unroll
  for (int hh = 0; hh < 8; hh++) {
    ph[hh] = o0 * pw[hh * D + t] + o1 * pw[hh * D + t + 256];
#pragma unroll
    for (int off = 32; off > 0; off >>= 1) ph[hh] += __shfl_xor(ph[hh], off, 64);
  }
  if (lane == 0) {
#pragma unroll
    for (int hh = 0; hh < 8; hh++) smp[wid][hh] = ph[hh];
  }
  __syncthreads();
  if (t < 8)
    phase[(size_t)tok * NH + t] = smp[0][t] + smp[1][t] + smp[2][t] + smp[3][t] + pb[t];
}

// ---------------- residual + layernorm (x fp32 in-place; y is bf16) ----------------
__global__ __launch_bounds__(256) void residual_ln_kernel(
    float* __restrict__ x, const short* __restrict__ y,
    const float* __restrict__ sc, const float* __restrict__ bi,
    short* __restrict__ xb) {
  __shared__ float sms[4][2];
  int tok = blockIdx.x, t = threadIdx.x, wid = t >> 6, lane = t & 63;
  float v0 = x[(size_t)tok * D + t] + bf2f(y[(size_t)tok * D + t]);
  float v1 = x[(size_t)tok * D + t + 256] + bf2f(y[(size_t)tok * D + t + 256]);
  float s = v0 + v1, q = v0 * v0 + v1 * v1;
#pragma unroll
  for (int off = 32; off > 0; off >>= 1) {
    s += __shfl_xor(s, off, 64);
    q += __shfl_xor(q, off, 64);
  }
  if (lane == 0) { sms[wid][0] = s; sms[wid][1] = q; }
  __syncthreads();
  float S = sms[0][0] + sms[1][0] + sms[2][0] + sms[3][0];
  float Q = sms[0][1] + sms[1][1] + sms[2][1] + sms[3][1];
  float mean = S * (1.0f / D);
  float var = Q * (1.0f / D) - mean * mean;
  float rstd = rsqrtf(var + EPS);
  float o0 = (v0 - mean) * rstd * sc[t] + bi[t];
  float o1 = (v1 - mean) * rstd * sc[t + 256] + bi[t + 256];
  x[(size_t)tok * D + t] = o0;
  x[(size_t)tok * D + t + 256] = o1;
  xb[(size_t)tok * D + t] = f2bf(o0);
  xb[(size_t)tok * D + t + 256] = f2bf(o1);
}

// ================= 2-phase dbuf GEMM, BM=128 (head only) =================
// MODE 0: fp32 plain  1: fp32 NT (coalesced via LDS).  SWAP: bm fastest.
template <int MODE, bool SWAP>
__global__ __launch_bounds__(256) void gemm128_kernel(
    const short* __restrict__ A, const short* __restrict__ W,
    const float* __restrict__ bias, float* __restrict__ C,
    int M, int N, int K, int act) {
  __shared__ char smem[32768];
  short* AsF = (short*)smem;            // [2][128][32] bf16 = 16 KB
  short* WsF = (short*)(smem + 16384);  // [2][128][32] bf16 = 16 KB
  int tid = threadIdx.x;
  int bn, bm;
  if (SWAP) { bm = blockIdx.x * 128; bn = blockIdx.y * 128; }
  else      { bn = blockIdx.x * 128; bm = blockIdx.y * 128; }
  int wid = tid >> 6, lane = tid & 63;
  int wm = (wid >> 1) * 64, wn = (wid & 1) * 64;
  int fr = lane & 15, kg = lane >> 4;
  f32x4 acc[4][4] = {};
  int srow = 32 * wid + (lane >> 2);
  int scol = (lane & 3) * 8;
  const short* Ag0 = A + (size_t)(bm + srow) * K + scol;
  const short* Ag1 = Ag0 + (size_t)16 * K;
  int wr0 = bn + srow;       if (wr0 >= N) wr0 = N - 1;
  int wr1 = bn + srow + 16;  if (wr1 >= N) wr1 = N - 1;
  const short* Wg0 = W + (size_t)wr0 * K + scol;
  const short* Wg1 = W + (size_t)wr1 * K + scol;
  auto stage = [&](int buf, int k0) {
    gload16(Ag0 + k0, AsF + buf * 4096 + (32 * wid) * 32);
    gload16(Ag1 + k0, AsF + buf * 4096 + (32 * wid + 16) * 32);
    gload16(Wg0 + k0, WsF + buf * 4096 + (32 * wid) * 32);
    gload16(Wg1 + k0, WsF + buf * 4096 + (32 * wid + 16) * 32);
  };
  stage(0, 0);
  __syncthreads();
  int nt = K / 32, cur = 0;
  for (int t = 0; t < nt; ++t) {
    if (t + 1 < nt) stage(cur ^ 1, (t + 1) * 32);
    const short* ab = AsF + cur * 4096;
    const short* wb = WsF + cur * 4096;
    s8v af[4], bfv[4];
#pragma unroll
    for (int m = 0; m < 4; m++) af[m] = *(const s8v*)(ab + (wm + m * 16 + fr) * 32 + kg * 8);
#pragma unroll
    for (int n = 0; n < 4; n++) bfv[n] = *(const s8v*)(wb + (wn + n * 16 + fr) * 32 + kg * 8);
#pragma unroll
    for (int m = 0; m < 4; m++)
#pragma unroll
      for (int n = 0; n < 4; n++)
        acc[m][n] = __builtin_amdgcn_mfma_f32_16x16x32_bf16(af[m], bfv[n], acc[m][n], 0, 0, 0);
    __syncthreads();
    cur ^= 1;
  }
  // ---- fp32 epilogue: 2 chunks of 64 rows x 128 cols through LDS, coalesced (NT) ----
  float* eps = (float*)smem;   // 64*128*4 = 32 KB
#pragma unroll
  for (int c = 0; c < 2; ++c) {
    __syncthreads();
    if ((wid >> 1) == c) {
#pragma unroll
      for (int n = 0; n < 4; n++) {
        int col = wn + n * 16 + fr;
        int gcol = bn + col;
        float bv = bias ? bias[gcol < N ? gcol : N - 1] : 0.0f;
#pragma unroll
        for (int m = 0; m < 4; m++)
#pragma unroll
          for (int r = 0; r < 4; r++)
            eps[(m * 16 + kg * 4 + r) * 128 + col] = act_apply(acc[m][n][r] + bv, act);
      }
    }
    __syncthreads();
#pragma unroll
    for (int i = 0; i < 8; i++) {
      int idx = tid + i * 256;
      int rl = idx >> 5;
      int c4 = (idx & 31) * 4;
      int row = bm + c * 64 + rl;
      int col = bn + c4;
      f4v v = *(f4v*)&eps[rl * 128 + c4];
      float* dst = C + (size_t)row * N + col;
      if (col + 3 < N) {
        if (MODE == 1) __builtin_nontemporal_store(v, (f4v*)dst);
        else *(f4v*)dst = v;
      } else {
        for (int j = 0; j < 4; j++)
          if (col + j < N) {
            if (MODE == 1) __builtin_nontemporal_store(v[j], dst + j);
            else dst[j] = v[j];
          }
      }
    }
  }
}

// ================= 2-phase dbuf GEMM, BM=64 =================
// OUTBF: LDS-staged coalesced bf16 epilogue (requires N % 128 == 0).
// Vt != nullptr (qkv GEMM): bn >= 1024 tiles are V -> transposed scatter to Vt[B][H][DH][L]
template <bool OUTBF>
__global__ __launch_bounds__(256) void gemm64_kernel(
    const short* __restrict__ A, const short* __restrict__ W,
    const float* __restrict__ bias, float* __restrict__ C, short* __restrict__ Cb,
    short* __restrict__ Vt, int M, int N, int K, int act) {
  __shared__ char smem[24576];
  short* AsF = (short*)smem;            // [2][64][32] = 8 KB
  short* WsF = (short*)(smem + 8192);   // [2][128][32] = 16 KB
  int tid = threadIdx.x;
  int bn = blockIdx.x * 128, bm = blockIdx.y * 64;
  int wid = tid >> 6, lane = tid & 63;
  int fr = lane & 15, kg = lane >> 4;
  f32x4 acc[4][2] = {};
  int l4 = lane >> 2;
  int scol = (lane & 3) * 8;
  const short* Ag0 = A + (size_t)(bm + 16 * wid + l4) * K + scol;
  int wr0 = bn + 32 * wid + l4;       if (wr0 >= N) wr0 = N - 1;
  int wr1 = bn + 32 * wid + 16 + l4;  if (wr1 >= N) wr1 = N - 1;
  const short* Wg0 = W + (size_t)wr0 * K + scol;
  const short* Wg1 = W + (size_t)wr1 * K + scol;
  auto stage = [&](int buf, int k0) {
    gload16(Ag0 + k0, AsF + buf * 2048 + (16 * wid) * 32);
    gload16(Wg0 + k0, WsF + buf * 4096 + (32 * wid) * 32);
    gload16(Wg1 + k0, WsF + buf * 4096 + (32 * wid + 16) * 32);
  };
  stage(0, 0);
  __syncthreads();
  int nt = K / 32, cur = 0;
  for (int t = 0; t < nt; ++t) {
    if (t + 1 < nt) stage(cur ^ 1, (t + 1) * 32);
    const short* ab = AsF + cur * 2048;
    const short* wb = WsF + cur * 4096;
    s8v af[4], bfv[2];
#pragma unroll
    for (int m = 0; m < 4; m++) af[m] = *(const s8v*)(ab + (m * 16 + fr) * 32 + kg * 8);
#pragma unroll
    for (int n = 0; n < 2; n++) bfv[n] = *(const s8v*)(wb + (wid * 32 + n * 16 + fr) * 32 + kg * 8);
#pragma unroll
    for (int m = 0; m < 4; m++)
#pragma unroll
      for (int n = 0; n < 2; n++)
        acc[m][n] = __builtin_amdgcn_mfma_f32_16x16x32_bf16(af[m], bfv[n], acc[m][n], 0, 0, 0);
    __syncthreads();
    cur ^= 1;
  }
  int rbase = bm + kg * 4;
  if (Vt != nullptr && bn >= 1024) {    // pure-V tile: transposed scatter (packed along L)
#pragma unroll
    for (int n = 0; n < 2; n++) {
      int col = bn + wid * 32 + n * 16 + fr;
      float bv = bias ? bias[col] : 0.0f;
      int hh = (col - 1024) >> 6, dd = (col - 1024) & 63;
#pragma unroll
      for (int m = 0; m < 4; m++) {
        int row0 = rbase + m * 16;        // multiple of 4
        int bb = row0 >> 10, ll = row0 & 1023;
        short4 pk;
        pk.x = f2bf(acc[m][n][0] + bv);
        pk.y = f2bf(acc[m][n][1] + bv);
        pk.z = f2bf(acc[m][n][2] + bv);
        pk.w = f2bf(acc[m][n][3] + bv);
        *(short4*)&Vt[((((size_t)bb * NH + hh) * DH + dd) << 10) | ll] = pk;
      }
    }
    return;
  }
  if (OUTBF) {
    // ---- LDS-staged coalesced bf16 epilogue: 64 rows x 128 cols = 16 KB ----
    short* eph = (short*)smem;
    __syncthreads();
#pragma unroll
    for (int n = 0; n < 2; n++) {
      int col = wid * 32 + n * 16 + fr;
      float bv = bias ? bias[bn + col] : 0.0f;
#pragma unroll
      for (int m = 0; m < 4; m++)
#pragma unroll
        for (int r = 0; r < 4; r++)
          eph[(kg * 4 + m * 16 + r) * 128 + col] = f2bf(act_apply(acc[m][n][r] + bv, act));
    }
    __syncthreads();
#pragma unroll
    for (int i = 0; i < 4; i++) {
      int idx = tid + i * 256;
      int rl = idx >> 4;
      int c8 = (idx & 15) * 8;
      *(s8v*)&Cb[(size_t)(bm + rl) * N + bn + c8] = *(s8v*)&eph[rl * 128 + c8];
    }
  } else {
#pragma unroll
    for (int n = 0; n < 2; n++) {
      int col = bn + wid * 32 + n * 16 + fr;
      if (col >= N) continue;
      float bv = bias ? bias[col] : 0.0f;
#pragma unroll
      for (int m = 0; m < 4; m++)
#pragma unroll
        for (int r = 0; r < 4; r++)
          C[(size_t)(rbase + m * 16 + r) * N + col] = act_apply(acc[m][n][r] + bv, act);
    }
  }
}

// ---------------- fallback GEMM (fp32 weights converted in staging) ----------------
template <bool OUTBF>
__global__ __launch_bounds__(256) void gemm_conv_kernel(
    const short* __restrict__ A, const float* __restrict__ Wp,
    const float* __restrict__ bias, float* __restrict__ C, short* __restrict__ Cb,
    short* __restrict__ Vt, int M, int N, int K, int act) {
  __shared__ short As[128][40];
  __shared__ short Ws[128][40];
  int tid = threadIdx.x;
  int bn = blockIdx.x * 128, bm = blockIdx.y * 128;
  int wid = tid >> 6, lane = tid & 63;
  int wm = (wid >> 1) * 64, wn = (wid & 1) * 64;
  int fr = lane & 15, kg = lane >> 4;
  f32x4 acc[4][4] = {};
  int sr = tid >> 1;
  int sc = (tid & 1) * 16;
  const short* Arow = A + (size_t)(bm + sr) * K + sc;
  int wrow = bn + sr;
  int wclamp = wrow < N ? wrow : 0;
  const float* Wrow_f = Wp + (size_t)wclamp * K + sc;
  for (int k0 = 0; k0 < K; k0 += 32) {
    s8v a0 = *(const s8v*)(Arow + k0);
    s8v a1 = *(const s8v*)(Arow + k0 + 8);
    s8v w0, w1;
    float4 f0 = *(const float4*)(Wrow_f + k0);
    float4 f1 = *(const float4*)(Wrow_f + k0 + 4);
    float4 f2 = *(const float4*)(Wrow_f + k0 + 8);
    float4 f3 = *(const float4*)(Wrow_f + k0 + 12);
    w0[0] = f2bf(f0.x); w0[1] = f2bf(f0.y); w0[2] = f2bf(f0.z); w0[3] = f2bf(f0.w);
    w0[4] = f2bf(f1.x); w0[5] = f2bf(f1.y); w0[6] = f2bf(f1.z); w0[7] = f2bf(f1.w);
    w1[0] = f2bf(f2.x); w1[1] = f2bf(f2.y); w1[2] = f2bf(f2.z); w1[3] = f2bf(f2.w);
    w1[4] = f2bf(f3.x); w1[5] = f2bf(f3.y); w1[6] = f2bf(f3.z); w1[7] = f2bf(f3.w);
    __syncthreads();
    *(s8v*)&As[sr][sc] = a0;
    *(s8v*)&As[sr][sc + 8] = a1;
    *(s8v*)&Ws[sr][sc] = w0;
    *(s8v*)&Ws[sr][sc + 8] = w1;
    __syncthreads();
    s8v af[4], bfv[4];
#pragma unroll
    for (int m = 0; m < 4; m++) af[m] = *(const s8v*)&As[wm + m * 16 + fr][kg * 8];
#pragma unroll
    for (int n = 0; n < 4; n++) bfv[n] = *(const s8v*)&Ws[wn + n * 16 + fr][kg * 8];
#pragma unroll
    for (int m = 0; m < 4; m++)
#pragma unroll
      for (int n = 0; n < 4; n++)
        acc[m][n] = __builtin_amdgcn_mfma_f32_16x16x32_bf16(af[m], bfv[n], acc[m][n], 0, 0, 0);
  }
  int rbase = bm + wm + kg * 4;
#pragma unroll
  for (int n = 0; n < 4; n++) {
    int col = bn + wn + n * 16 + fr;
    if (col >= N) continue;
    float bv = bias ? bias[col] : 0.0f;
    if (Vt != nullptr && col >= 1024) {
      int hh = (col - 1024) >> 6, dd = (col - 1024) & 63;
#pragma unroll
      for (int m = 0; m < 4; m++) {
        int row0 = rbase + m * 16;
        int bb = row0 >> 10, ll = row0 & 1023;
        short4 pk;
        pk.x = f2bf(acc[m][n][0] + bv);
        pk.y = f2bf(acc[m][n][1] + bv);
        pk.z = f2bf(acc[m][n][2] + bv);
        pk.w = f2bf(acc[m][n][3] + bv);
        *(short4*)&Vt[((((size_t)bb * NH + hh) * DH + dd) << 10) | ll] = pk;
      }
      continue;
    }
#pragma unroll
    for (int m = 0; m < 4; m++) {
#pragma unroll
      for (int r = 0; r < 4; r++) {
        int row = rbase + m * 16 + r;
        float v = act_apply(acc[m][n][r] + bv, act);
        if (OUTBF) Cb[(size_t)row * N + col] = f2bf(v);
        else C[(size_t)row * N + col] = v;
      }
    }
  }
}

// ---------------- MFMA flash attention (V pre-transposed) ----------------
__global__ __launch_bounds__(256) void mha_kernel(
    const short* __restrict__ qkv, const short* __restrict__ vt,
    const float* __restrict__ phase, short* __restrict__ out) {
  __shared__ short sQ[64][72];
  __shared__ short sK[64][72];
  __shared__ short sVt[64][72];
  __shared__ short sP[64][72];
  __shared__ float sPh[Lseq];
  int bh = blockIdx.y;
  int b = bh >> 3, h = bh & 7;
  int q0 = blockIdx.x * 64;
  int tid = threadIdx.x;
  int lane = tid & 63, wid = tid >> 6;
  int fr = lane & 15, kg = lane >> 4;
  int wm = wid * 16;
  const short* vtb = vt + ((size_t)bh * DH) * Lseq;

  for (int j = tid; j < Lseq; j += 256) sPh[j] = phase[((size_t)(b * Lseq + j)) * NH + h];
  for (int idx = tid; idx < 512; idx += 256) {
    int row = idx >> 3, c8 = (idx & 7) * 8;
    *(s8v*)&sQ[row][c8] =
        *(const s8v*)(qkv + (((size_t)(b * Lseq + q0 + row)) * 3 + 0) * D + h * DH + c8);
  }
  __syncthreads();

  float phq[4];
#pragma unroll
  for (int r = 0; r < 4; r++) phq[r] = sPh[q0 + wm + kg * 4 + r];

  float mrow[4] = {-1e30f, -1e30f, -1e30f, -1e30f};
  float lrow[4] = {0.f, 0.f, 0.f, 0.f};
  f32x4 o[4] = {};

  for (int kt = 0; kt < Lseq / 64; kt++) {
    int k0 = kt * 64;
    __syncthreads();
    for (int idx = tid; idx < 512; idx += 256) {
      int row = idx >> 3, c8 = (idx & 7) * 8;
      *(s8v*)&sK[row][c8] =
          *(const s8v*)(qkv + (((size_t)(b * Lseq + k0 + row)) * 3 + 1) * D + h * DH + c8);
      *(s8v*)&sVt[row][c8] = *(const s8v*)(vtb + (size_t)row * Lseq + k0 + c8);
    }
    __syncthreads();

    s8v qa0 = *(const s8v*)&sQ[wm + fr][kg * 8];
    s8v qa1 = *(const s8v*)&sQ[wm + fr][32 + kg * 8];
    f32x4 sacc[4];
#pragma unroll
    for (int n = 0; n < 4; n++) {
      f32x4 z = {};
      s8v kb0 = *(const s8v*)&sK[n * 16 + fr][kg * 8];
      s8v kb1 = *(const s8v*)&sK[n * 16 + fr][32 + kg * 8];
      z = __builtin_amdgcn_mfma_f32_16x16x32_bf16(qa0, kb0, z, 0, 0, 0);
      z = __builtin_amdgcn_mfma_f32_16x16x32_bf16(qa1, kb1, z, 0, 0, 0);
      sacc[n] = z;
    }
    float sv[4][4];
#pragma unroll
    for (int n = 0; n < 4; n++) {
      float phk = sPh[k0 + n * 16 + fr];
#pragma unroll
      for (int r = 0; r < 4; r++) {
        float dp = phq[r] - phk;
        sv[n][r] = sacc[n][r] * 0.125f - dp * dp;
      }
    }
    float mnew[4], alpha[4];
#pragma unroll
    for (int r = 0; r < 4; r++) {
      float mx = fmaxf(fmaxf(sv[0][r], sv[1][r]), fmaxf(sv[2][r], sv[3][r]));
#pragma unroll
      for (int off = 1; off < 16; off <<= 1) mx = fmaxf(mx, __shfl_xor(mx, off, 64));
      mnew[r] = fmaxf(mrow[r], mx);
      alpha[r] = __expf(mrow[r] - mnew[r]);
      mrow[r] = mnew[r];
    }
    float rs[4] = {0.f, 0.f, 0.f, 0.f};
#pragma unroll
    for (int n = 0; n < 4; n++) {
#pragma unroll
      for (int r = 0; r < 4; r++) {
        float p = __expf(sv[n][r] - mnew[r]);
        rs[r] += p;
        sP[wm + kg * 4 + r][n * 16 + fr] = f2bf(p);
      }
    }
#pragma unroll
    for (int r = 0; r < 4; r++) {
#pragma unroll
      for (int off = 1; off < 16; off <<= 1) rs[r] += __shfl_xor(rs[r], off, 64);
      lrow[r] = lrow[r] * alpha[r] + rs[r];
    }
#pragma unroll
    for (int df = 0; df < 4; df++) {
      o[df][0] *= alpha[0]; o[df][1] *= alpha[1];
      o[df][2] *= alpha[2]; o[df][3] *= alpha[3];
    }
    s8v pa0 = *(const s8v*)&sP[wm + fr][kg * 8];
    s8v pa1 = *(const s8v*)&sP[wm + fr][32 + kg * 8];
#pragma unroll
    for (int df = 0; df < 4; df++) {
      int d = df * 16 + fr;
      s8v vb0 = *(const s8v*)&sVt[d][kg * 8];
      s8v vb1 = *(const s8v*)&sVt[d][32 + kg * 8];
      o[df] = __builtin_amdgcn_mfma_f32_16x16x32_bf16(pa0, vb0, o[df], 0, 0, 0);
      o[df] = __builtin_amdgcn_mfma_f32_16x16x32_bf16(pa1, vb1, o[df], 0, 0, 0);
    }
  }
  float inv[4];
#pragma unroll
  for (int r = 0; r < 4; r++) inv[r] = 1.0f / lrow[r];
#pragma unroll
  for (int df = 0; df < 4; df++) {
#pragma unroll
    for (int r = 0; r < 4; r++) {
      int row = q0 + wm + kg * 4 + r;
      out[((size_t)(b * Lseq + row)) * D + h * DH + df * 16 + fr] = f2bf(o[df][r] * inv[r]);
    }
  }
}

// ---------------- fused boundary gate + xg = bf16(x * gate) ----------------
__global__ __launch_bounds__(128) void gatexg_kernel(
    const float* __restrict__ tb, const float* __restrict__ w2,
    const float* __restrict__ b2, const float* __restrict__ x,
    float* __restrict__ gate, short* __restrict__ xg) {
  __shared__ float sred[2];
  int tok = blockIdx.x, t = threadIdx.x;   // 128 threads = 2 waves
  const float* row = tb + (size_t)tok * D;
  float acc = row[t] * w2[t] + row[t + 128] * w2[t + 128] +
              row[t + 256] * w2[t + 256] + row[t + 384] * w2[t + 384];
#pragma unroll
  for (int off = 32; off > 0; off >>= 1) acc += __shfl_xor(acc, off, 64);
  if ((t & 63) == 0) sred[t >> 6] = acc;
  __syncthreads();
  float g = 1.0f / (1.0f + expf(-(sred[0] + sred[1] + b2[0])));
  if (t == 0) gate[tok] = g;
  float4 v = *(const float4*)(x + (size_t)tok * D + t * 4);
  short4 o = make_short4(f2bf(v.x * g), f2bf(v.y * g), f2bf(v.z * g), f2bf(v.w * g));
  *(short4*)(xg + (size_t)tok * D + t * 4) = o;
}

extern "C" void kernel_launch(void* const* d_in, const int* in_sizes, int n_in,
                              void* d_out, int out_size, void* d_ws, size_t ws_size,
                              hipStream_t stream) {
  const int* ids = (const int*)d_in[0];
  const float* emb = (const float*)d_in[1];
  const float* pos = (const float*)d_in[2];
  const float* rg_w = (const float*)d_in[3];
  const float* rg_b = (const float*)d_in[4];
  const float* qkv_w = (const float*)d_in[5];
  const float* qkv_b = (const float*)d_in[6];
  const float* out_w = (const float*)d_in[7];
  const float* out_b = (const float*)d_in[8];
  const float* ph_w = (const float*)d_in[9];
  const float* ph_b = (const float*)d_in[10];
  const float* ff1_w = (const float*)d_in[11];
  const float* ff1_b = (const float*)d_in[12];
  const float* ff2_w = (const float*)d_in[13];
  const float* ff2_b = (const float*)d_in[14];
  const float* n1_s = (const float*)d_in[15];
  const float* n1_b = (const float*)d_in[16];
  const float* n2_s = (const float*)d_in[17];
  const float* n2_b = (const float*)d_in[18];
  const float* bw1 = (const float*)d_in[19];
  const float* bb1 = (const float*)d_in[20];
  const float* bw2 = (const float*)d_in[21];
  const float* bb2 = (const float*)d_in[22];
  const float* head_w = (const float*)d_in[23];

  char* w = (char*)d_ws;
  float* x      = (float*)(w + 0);           //  8.39 MB
  float* ao     = (float*)(w + 8388608);     //  8.39 MB (bnd tanh-buf; first 4.2 MB doubles as y_bf)
  short* y_bf   = (short*)(w + 8388608);     //  4.19 MB (residual-add input, bf16)
  float* phase  = (float*)(w + 16777216);    //  0.13 MB
  short* h_bf   = (short*)(w + 16908288);    //  4.19 MB
  short* ao_bf  = (short*)(w + 21102592);    //  4.19 MB
  short* x_bf   = (short*)(w + 25296896);    //  4.19 MB
  short* ff_bf  = (short*)(w + 29491200);    // 16.78 MB
  short* xg_bf  = (short*)(w + 46268416);    //  4.19 MB
  short* qkv_bf = (short*)(w + 50462720);    // 12.58 MB
  short* vt_bf  = (short*)(w + 63045632);    //  4.19 MB
  short* wqkv   = (short*)(w + 67239936);    //  9.44 MB
  short* wout   = (short*)(w + 76677120);    //  3.15 MB
  short* wff1   = (short*)(w + 79822848);    // 12.58 MB
  short* wff2   = (short*)(w + 92405760);    // 12.58 MB
  short* wbnd   = (short*)(w + 104988672);   //  0.52 MB
  short* whead  = (short*)(w + 105512960);   // 30.72 MB
  const size_t WS_FULL = 136232960;

  float* outf   = (float*)d_out;
  float* logits = outf;
  float* gate   = outf + 122880000;
  float* rg_out = outf + 122884096;

  bool fast = ws_size >= WS_FULL;

  if (fast) {
    f2bf6_kernel<<<(34496512 / 8 + 255) / 256, 256, 0, stream>>>(
        qkv_w, wqkv, 4718592, out_w, wout, 1572864, ff1_w, wff1, 6291456,
        ff2_w, wff2, 6291456, bw1, wbnd, 262144, head_w, whead, 15360000);
  }

  embed_kernel<<<BL, 128, 0, stream>>>(ids, emb, pos, x);

  for (int l = 0; l < NL; l++) {
    rg_ln_kernel<<<BL, 256, 0, stream>>>(
        x, rg_w + (size_t)l * 4 * D, rg_b + l * 4, n1_s + l * D, n1_b + l * D,
        ph_w + (size_t)l * NH * D, ph_b + l * NH,
        h_bf, phase, (l == NL - 1) ? rg_out : nullptr);
    if (fast)
      gemm64_kernel<true><<<dim3(12, 64), 256, 0, stream>>>(
          h_bf, wqkv + (size_t)l * 1536 * D, qkv_b + l * 1536, nullptr, qkv_bf, vt_bf,
          BL, 1536, D, 0);
    else
      gemm_conv_kernel<true><<<dim3(12, 32), 256, 0, stream>>>(
          h_bf, qkv_w + (size_t)l * 1536 * D, qkv_b + l * 1536, nullptr, qkv_bf, vt_bf,
          BL, 1536, D, 0);
    mha_kernel<<<dim3(Lseq / 64, Bsz * NH), 256, 0, stream>>>(qkv_bf, vt_bf, phase, ao_bf);
    if (fast)
      gemm64_kernel<true><<<dim3(4, 64), 256, 0, stream>>>(
          ao_bf, wout + (size_t)l * D * D, out_b + l * D, nullptr, y_bf, nullptr, BL, D, D, 0);
    else
      gemm_conv_kernel<true><<<dim3(4, 32), 256, 0, stream>>>(
          ao_bf, out_w + (size_t)l * D * D, out_b + l * D, nullptr, y_bf, nullptr, BL, D, D, 0);
    residual_ln_kernel<<<BL, 256, 0, stream>>>(x, y_bf, n1_s + l * D, n1_b + l * D, x_bf);
    if (fast)
      gemm64_kernel<true><<<dim3(16, 64), 256, 0, stream>>>(
          x_bf, wff1 + (size_t)l * 2048 * D, ff1_b + l * 2048, nullptr, ff_bf, nullptr,
          BL, 2048, D, 1);
    else
      gemm_conv_kernel<true><<<dim3(16, 32), 256, 0, stream>>>(
          x_bf, ff1_w + (size_t)l * 2048 * D, ff1_b + l * 2048, nullptr, ff_bf, nullptr,
          BL, 2048, D, 1);
    if (fast)
      gemm64_kernel<true><<<dim3(4, 64), 256, 0, stream>>>(
          ff_bf, wff2 + (size_t)l * D * 2048, ff2_b + l * D, nullptr, y_bf, nullptr,
          BL, D, 2048, 0);
    else
      gemm_conv_kernel<true><<<dim3(4, 32), 256, 0, stream>>>(
          ff_bf, ff2_w + (size_t)l * D * 2048, ff2_b + l * D, nullptr, y_bf, nullptr,
          BL, D, 2048, 0);
    residual_ln_kernel<<<BL, 256, 0, stream>>>(x, y_bf, n2_s + l * D, n2_b + l * D, x_bf);
  }

  if (fast)
    gemm64_kernel<false><<<dim3(4, 64), 256, 0, stream>>>(
        x_bf, wbnd, bb1, ao, nullptr, nullptr, BL, D, D, 2);
  else
    gemm_conv_kernel<false><<<dim3(4, 32), 256, 0, stream>>>(
        x_bf, bw1, bb1, ao, nullptr, nullptr, BL, D, D, 2);
  gatexg_kernel<<<BL, 128, 0, stream>>>(ao, bw2, bb2, x, gate, xg_bf);
  if (fast)
    gemm128_kernel<1, true><<<dim3(32, 235), 256, 0, stream>>>(
        xg_bf, whead, nullptr, logits, BL, Vocab, D, 0);
  else
    gemm_conv_kernel<false><<<dim3(235, 32), 256, 0, stream>>>(
        xg_bf, head_w, nullptr, logits, nullptr, nullptr, BL, Vocab, D, 0);
}

// Round 15
// 1153.624 us; speedup vs baseline: 1.1508x; 1.0579x over previous
//
#include <hip/hip_runtime.h>
#include <math.h>

#define D 512
#define NH 8
#define DH 64
#define NL 6
#define Bsz 4
#define Lseq 1024
#define BL 4096          // B*L tokens
#define Vocab 30000
#define EPS 1e-5f

typedef __attribute__((ext_vector_type(8))) short s8v;   // 8 bf16 (4 VGPRs)
typedef __attribute__((ext_vector_type(4))) float f32x4; // MFMA accumulator
typedef __attribute__((ext_vector_type(4))) float f4v;   // clang vector (NT-store OK)

__device__ __forceinline__ float sigmoidf_(float x) { return 1.0f / (1.0f + expf(-x)); }

__device__ __forceinline__ short f2bf(float f) {  // fp32 -> bf16 bits, RNE
  union { float f; unsigned u; } v; v.f = f;
  return (short)((v.u + 0x7FFFu + ((v.u >> 16) & 1u)) >> 16);
}
__device__ __forceinline__ float bf2f(short s) {
  union { unsigned u; float f; } v; v.u = ((unsigned)(unsigned short)s) << 16;
  return v.f;
}

// async global->LDS, 16B per lane. LDS dest is wave-uniform base; HW adds lane*16.
__device__ __forceinline__ void gload16(const void* g, void* l) {
  __builtin_amdgcn_global_load_lds(
      (const __attribute__((address_space(1))) void*)g,
      (__attribute__((address_space(3))) void*)l, 16, 0, 0);
}

__device__ __forceinline__ float act_apply(float v, int act) {
  if (act == 1) return 0.5f * v * (1.0f + erff(v * 0.7071067811865475f));
  if (act == 2) return tanhf(v);
  return v;
}

// ---------------- fp32 -> bf16 bulk convert: 6 segments in one launch ----------------
__global__ void f2bf6_kernel(
    const float* __restrict__ s0, short* __restrict__ d0, int n0,
    const float* __restrict__ s1, short* __restrict__ d1, int n1,
    const float* __restrict__ s2, short* __restrict__ d2, int n2,
    const float* __restrict__ s3, short* __restrict__ d3, int n3,
    const float* __restrict__ s4, short* __restrict__ d4, int n4,
    const float* __restrict__ s5, short* __restrict__ d5, int n5) {
  long i = ((long)blockIdx.x * 256 + threadIdx.x) * 8;
  const float* s; short* d;
  if (i < n0) { s = s0; d = d0; }
  else {
    i -= n0;
    if (i < n1) { s = s1; d = d1; }
    else {
      i -= n1;
      if (i < n2) { s = s2; d = d2; }
      else {
        i -= n2;
        if (i < n3) { s = s3; d = d3; }
        else {
          i -= n3;
          if (i < n4) { s = s4; d = d4; }
          else { i -= n4; if (i >= n5) return; s = s5; d = d5; }
        }
      }
    }
  }
  float4 a = *(const float4*)(s + i);
  float4 b = *(const float4*)(s + i + 4);
  s8v o;
  o[0] = f2bf(a.x); o[1] = f2bf(a.y); o[2] = f2bf(a.z); o[3] = f2bf(a.w);
  o[4] = f2bf(b.x); o[5] = f2bf(b.y); o[6] = f2bf(b.z); o[7] = f2bf(b.w);
  *(s8v*)(d + i) = o;
}

// ---------------- embed + pos ----------------
__global__ void embed_kernel(const int* __restrict__ ids, const float* __restrict__ emb,
                             const float* __restrict__ pos, float* __restrict__ x) {
  int tok = blockIdx.x;
  int l = tok & (Lseq - 1);
  int id = ids[tok];
  const float4* e = (const float4*)(emb + (size_t)id * D);
  const float4* p = (const float4*)(pos + (size_t)l * D);
  float4* o = (float4*)(x + (size_t)tok * D);
  float4 a = e[threadIdx.x], b = p[threadIdx.x];
  o[threadIdx.x] = make_float4(a.x + b.x, a.y + b.y, a.z + b.z, a.w + b.w);
}

// ---------- fused rg gate + modulate + layernorm -> bf16 h, + phase (h.pw^T) ----------
__global__ __launch_bounds__(256) void rg_ln_kernel(
    const float* __restrict__ x, const float* __restrict__ rgw, const float* __restrict__ rgb,
    const float* __restrict__ sc, const float* __restrict__ bi,
    const float* __restrict__ pw, const float* __restrict__ pb,
    short* __restrict__ h, float* __restrict__ phase, float* __restrict__ rg_out) {
  __shared__ float smg[4][4];
  __shared__ float sms[4][2];
  __shared__ float smh[512];
  int tok = blockIdx.x, t = threadIdx.x, wid = t >> 6, lane = t & 63;
  const float* xr = x + (size_t)tok * D;
  float x0 = xr[t], x1 = xr[t + 256];
  float p0 = x0 * rgw[t]        + x1 * rgw[t + 256];
  float p1 = x0 * rgw[512 + t]  + x1 * rgw[512 + t + 256];
  float p2 = x0 * rgw[1024 + t] + x1 * rgw[1024 + t + 256];
  float p3 = x0 * rgw[1536 + t] + x1 * rgw[1536 + t + 256];
#pragma unroll
  for (int off = 32; off > 0; off >>= 1) {
    p0 += __shfl_xor(p0, off, 64);
    p1 += __shfl_xor(p1, off, 64);
    p2 += __shfl_xor(p2, off, 64);
    p3 += __shfl_xor(p3, off, 64);
  }
  if (lane == 0) { smg[wid][0] = p0; smg[wid][1] = p1; smg[wid][2] = p2; smg[wid][3] = p3; }
  __syncthreads();
  float g0 = sigmoidf_(smg[0][0] + smg[1][0] + smg[2][0] + smg[3][0] + rgb[0]);
  float g1 = sigmoidf_(smg[0][1] + smg[1][1] + smg[2][1] + smg[3][1] + rgb[1]);
  float g2 = sigmoidf_(smg[0][2] + smg[1][2] + smg[2][2] + smg[3][2] + rgb[2]);
  float g3 = sigmoidf_(smg[0][3] + smg[1][3] + smg[2][3] + smg[3][3] + rgb[3]);
  if (rg_out != nullptr && t == 0) {
    float* ro = rg_out + (size_t)tok * 4;
    ro[0] = g0; ro[1] = g1; ro[2] = g2; ro[3] = g3;
  }
  float mod = 1.0f + 0.25f * (g0 + g1 + g2 + g3);
  float m0 = x0 * mod, m1 = x1 * mod;
  float s = m0 + m1, q = m0 * m0 + m1 * m1;
#pragma unroll
  for (int off = 32; off > 0; off >>= 1) {
    s += __shfl_xor(s, off, 64);
    q += __shfl_xor(q, off, 64);
  }
  if (lane == 0) { sms[wid][0] = s; sms[wid][1] = q; }
  __syncthreads();
  float S = sms[0][0] + sms[1][0] + sms[2][0] + sms[3][0];
  float Q = sms[0][1] + sms[1][1] + sms[2][1] + sms[3][1];
  float mean = S * (1.0f / D);
  float var = Q * (1.0f / D) - mean * mean;
  float rstd = rsqrtf(var + EPS);
  float o0 = (m0 - mean) * rstd * sc[t] + bi[t];
  float o1 = (m1 - mean) * rstd * sc[t + 256] + bi[t + 256];
  h[(size_t)tok * D + t] = f2bf(o0);
  h[(size_t)tok * D + t + 256] = f2bf(o1);
  smh[t] = o0;
  smh[t + 256] = o1;
  __syncthreads();
  // phase: each wave reduces 2 heads from LDS-staged h
  const float4* hv = (const float4*)&smh[lane * 8];
  float4 a0 = hv[0], a1 = hv[1];
  float ph[2];
#pragma unroll
  for (int j = 0; j < 2; j++) {
    int hh = wid * 2 + j;
    const float4* wv = (const float4*)&pw[hh * D + lane * 8];
    float4 b0 = wv[0], b1 = wv[1];
    float acc = a0.x * b0.x + a0.y * b0.y + a0.z * b0.z + a0.w * b0.w +
                a1.x * b1.x + a1.y * b1.y + a1.z * b1.z + a1.w * b1.w;
#pragma unroll
    for (int off = 32; off > 0; off >>= 1) acc += __shfl_xor(acc, off, 64);
    ph[j] = acc;
  }
  if (lane == 0) {
    int hh = wid * 2;
    phase[(size_t)tok * NH + hh] = ph[0] + pb[hh];
    phase[(size_t)tok * NH + hh + 1] = ph[1] + pb[hh + 1];
  }
}

// ---------------- residual + layernorm (x fp32 in-place; y is bf16) ----------------
__global__ __launch_bounds__(256) void residual_ln_kernel(
    float* __restrict__ x, const short* __restrict__ y,
    const float* __restrict__ sc, const float* __restrict__ bi,
    short* __restrict__ xb) {
  __shared__ float sms[4][2];
  int tok = blockIdx.x, t = threadIdx.x, wid = t >> 6, lane = t & 63;
  float v0 = x[(size_t)tok * D + t] + bf2f(y[(size_t)tok * D + t]);
  float v1 = x[(size_t)tok * D + t + 256] + bf2f(y[(size_t)tok * D + t + 256]);
  float s = v0 + v1, q = v0 * v0 + v1 * v1;
#pragma unroll
  for (int off = 32; off > 0; off >>= 1) {
    s += __shfl_xor(s, off, 64);
    q += __shfl_xor(q, off, 64);
  }
  if (lane == 0) { sms[wid][0] = s; sms[wid][1] = q; }
  __syncthreads();
  float S = sms[0][0] + sms[1][0] + sms[2][0] + sms[3][0];
  float Q = sms[0][1] + sms[1][1] + sms[2][1] + sms[3][1];
  float mean = S * (1.0f / D);
  float var = Q * (1.0f / D) - mean * mean;
  float rstd = rsqrtf(var + EPS);
  float o0 = (v0 - mean) * rstd * sc[t] + bi[t];
  float o1 = (v1 - mean) * rstd * sc[t + 256] + bi[t + 256];
  x[(size_t)tok * D + t] = o0;
  x[(size_t)tok * D + t + 256] = o1;
  xb[(size_t)tok * D + t] = f2bf(o0);
  xb[(size_t)tok * D + t + 256] = f2bf(o1);
}

// ================= 2-phase dbuf GEMM, BM=128 (head only) =================
template <int MODE, bool SWAP>
__global__ __launch_bounds__(256) void gemm128_kernel(
    const short* __restrict__ A, const short* __restrict__ W,
    const float* __restrict__ bias, float* __restrict__ C,
    int M, int N, int K, int act) {
  __shared__ char smem[32768];
  short* AsF = (short*)smem;
  short* WsF = (short*)(smem + 16384);
  int tid = threadIdx.x;
  int bn, bm;
  if (SWAP) { bm = blockIdx.x * 128; bn = blockIdx.y * 128; }
  else      { bn = blockIdx.x * 128; bm = blockIdx.y * 128; }
  int wid = tid >> 6, lane = tid & 63;
  int wm = (wid >> 1) * 64, wn = (wid & 1) * 64;
  int fr = lane & 15, kg = lane >> 4;
  f32x4 acc[4][4] = {};
  int srow = 32 * wid + (lane >> 2);
  int scol = (lane & 3) * 8;
  const short* Ag0 = A + (size_t)(bm + srow) * K + scol;
  const short* Ag1 = Ag0 + (size_t)16 * K;
  int wr0 = bn + srow;       if (wr0 >= N) wr0 = N - 1;
  int wr1 = bn + srow + 16;  if (wr1 >= N) wr1 = N - 1;
  const short* Wg0 = W + (size_t)wr0 * K + scol;
  const short* Wg1 = W + (size_t)wr1 * K + scol;
  auto stage = [&](int buf, int k0) {
    gload16(Ag0 + k0, AsF + buf * 4096 + (32 * wid) * 32);
    gload16(Ag1 + k0, AsF + buf * 4096 + (32 * wid + 16) * 32);
    gload16(Wg0 + k0, WsF + buf * 4096 + (32 * wid) * 32);
    gload16(Wg1 + k0, WsF + buf * 4096 + (32 * wid + 16) * 32);
  };
  stage(0, 0);
  __syncthreads();
  int nt = K / 32, cur = 0;
  for (int t = 0; t < nt; ++t) {
    if (t + 1 < nt) stage(cur ^ 1, (t + 1) * 32);
    const short* ab = AsF + cur * 4096;
    const short* wb = WsF + cur * 4096;
    s8v af[4], bfv[4];
#pragma unroll
    for (int m = 0; m < 4; m++) af[m] = *(const s8v*)(ab + (wm + m * 16 + fr) * 32 + kg * 8);
#pragma unroll
    for (int n = 0; n < 4; n++) bfv[n] = *(const s8v*)(wb + (wn + n * 16 + fr) * 32 + kg * 8);
#pragma unroll
    for (int m = 0; m < 4; m++)
#pragma unroll
      for (int n = 0; n < 4; n++)
        acc[m][n] = __builtin_amdgcn_mfma_f32_16x16x32_bf16(af[m], bfv[n], acc[m][n], 0, 0, 0);
    __syncthreads();
    cur ^= 1;
  }
  float* eps = (float*)smem;
#pragma unroll
  for (int c = 0; c < 2; ++c) {
    __syncthreads();
    if ((wid >> 1) == c) {
#pragma unroll
      for (int n = 0; n < 4; n++) {
        int col = wn + n * 16 + fr;
        int gcol = bn + col;
        float bv = bias ? bias[gcol < N ? gcol : N - 1] : 0.0f;
#pragma unroll
        for (int m = 0; m < 4; m++)
#pragma unroll
          for (int r = 0; r < 4; r++)
            eps[(m * 16 + kg * 4 + r) * 128 + col] = act_apply(acc[m][n][r] + bv, act);
      }
    }
    __syncthreads();
#pragma unroll
    for (int i = 0; i < 8; i++) {
      int idx = tid + i * 256;
      int rl = idx >> 5;
      int c4 = (idx & 31) * 4;
      int row = bm + c * 64 + rl;
      int col = bn + c4;
      f4v v = *(f4v*)&eps[rl * 128 + c4];
      float* dst = C + (size_t)row * N + col;
      if (col + 3 < N) {
        if (MODE == 1) __builtin_nontemporal_store(v, (f4v*)dst);
        else *(f4v*)dst = v;
      } else {
        for (int j = 0; j < 4; j++)
          if (col + j < N) {
            if (MODE == 1) __builtin_nontemporal_store(v[j], dst + j);
            else dst[j] = v[j];
          }
      }
    }
  }
}

// ================= 2-phase dbuf GEMM, BM=64 =================
template <bool OUTBF>
__global__ __launch_bounds__(256) void gemm64_kernel(
    const short* __restrict__ A, const short* __restrict__ W,
    const float* __restrict__ bias, float* __restrict__ C, short* __restrict__ Cb,
    short* __restrict__ Vt, int M, int N, int K, int act) {
  __shared__ char smem[24576];
  short* AsF = (short*)smem;
  short* WsF = (short*)(smem + 8192);
  int tid = threadIdx.x;
  int bn = blockIdx.x * 128, bm = blockIdx.y * 64;
  int wid = tid >> 6, lane = tid & 63;
  int fr = lane & 15, kg = lane >> 4;
  f32x4 acc[4][2] = {};
  int l4 = lane >> 2;
  int scol = (lane & 3) * 8;
  const short* Ag0 = A + (size_t)(bm + 16 * wid + l4) * K + scol;
  int wr0 = bn + 32 * wid + l4;       if (wr0 >= N) wr0 = N - 1;
  int wr1 = bn + 32 * wid + 16 + l4;  if (wr1 >= N) wr1 = N - 1;
  const short* Wg0 = W + (size_t)wr0 * K + scol;
  const short* Wg1 = W + (size_t)wr1 * K + scol;
  auto stage = [&](int buf, int k0) {
    gload16(Ag0 + k0, AsF + buf * 2048 + (16 * wid) * 32);
    gload16(Wg0 + k0, WsF + buf * 4096 + (32 * wid) * 32);
    gload16(Wg1 + k0, WsF + buf * 4096 + (32 * wid + 16) * 32);
  };
  stage(0, 0);
  __syncthreads();
  int nt = K / 32, cur = 0;
  for (int t = 0; t < nt; ++t) {
    if (t + 1 < nt) stage(cur ^ 1, (t + 1) * 32);
    const short* ab = AsF + cur * 2048;
    const short* wb = WsF + cur * 4096;
    s8v af[4], bfv[2];
#pragma unroll
    for (int m = 0; m < 4; m++) af[m] = *(const s8v*)(ab + (m * 16 + fr) * 32 + kg * 8);
#pragma unroll
    for (int n = 0; n < 2; n++) bfv[n] = *(const s8v*)(wb + (wid * 32 + n * 16 + fr) * 32 + kg * 8);
#pragma unroll
    for (int m = 0; m < 4; m++)
#pragma unroll
      for (int n = 0; n < 2; n++)
        acc[m][n] = __builtin_amdgcn_mfma_f32_16x16x32_bf16(af[m], bfv[n], acc[m][n], 0, 0, 0);
    __syncthreads();
    cur ^= 1;
  }
  int rbase = bm + kg * 4;
  if (Vt != nullptr && bn >= 1024) {
#pragma unroll
    for (int n = 0; n < 2; n++) {
      int col = bn + wid * 32 + n * 16 + fr;
      float bv = bias ? bias[col] : 0.0f;
      int hh = (col - 1024) >> 6, dd = (col - 1024) & 63;
#pragma unroll
      for (int m = 0; m < 4; m++) {
        int row0 = rbase + m * 16;
        int bb = row0 >> 10, ll = row0 & 1023;
        short4 pk;
        pk.x = f2bf(acc[m][n][0] + bv);
        pk.y = f2bf(acc[m][n][1] + bv);
        pk.z = f2bf(acc[m][n][2] + bv);
        pk.w = f2bf(acc[m][n][3] + bv);
        *(short4*)&Vt[((((size_t)bb * NH + hh) * DH + dd) << 10) | ll] = pk;
      }
    }
    return;
  }
  if (OUTBF) {
    short* eph = (short*)smem;
    __syncthreads();
#pragma unroll
    for (int n = 0; n < 2; n++) {
      int col = wid * 32 + n * 16 + fr;
      float bv = bias ? bias[bn + col] : 0.0f;
#pragma unroll
      for (int m = 0; m < 4; m++)
#pragma unroll
        for (int r = 0; r < 4; r++)
          eph[(kg * 4 + m * 16 + r) * 128 + col] = f2bf(act_apply(acc[m][n][r] + bv, act));
    }
    __syncthreads();
#pragma unroll
    for (int i = 0; i < 4; i++) {
      int idx = tid + i * 256;
      int rl = idx >> 4;
      int c8 = (idx & 15) * 8;
      *(s8v*)&Cb[(size_t)(bm + rl) * N + bn + c8] = *(s8v*)&eph[rl * 128 + c8];
    }
  } else {
#pragma unroll
    for (int n = 0; n < 2; n++) {
      int col = bn + wid * 32 + n * 16 + fr;
      if (col >= N) continue;
      float bv = bias ? bias[col] : 0.0f;
#pragma unroll
      for (int m = 0; m < 4; m++)
#pragma unroll
        for (int r = 0; r < 4; r++)
          C[(size_t)(rbase + m * 16 + r) * N + col] = act_apply(acc[m][n][r] + bv, act);
    }
  }
}

// ---------------- fallback GEMM (fp32 weights converted in staging) ----------------
template <bool OUTBF>
__global__ __launch_bounds__(256) void gemm_conv_kernel(
    const short* __restrict__ A, const float* __restrict__ Wp,
    const float* __restrict__ bias, float* __restrict__ C, short* __restrict__ Cb,
    short* __restrict__ Vt, int M, int N, int K, int act) {
  __shared__ short As[128][40];
  __shared__ short Ws[128][40];
  int tid = threadIdx.x;
  int bn = blockIdx.x * 128, bm = blockIdx.y * 128;
  int wid = tid >> 6, lane = tid & 63;
  int wm = (wid >> 1) * 64, wn = (wid & 1) * 64;
  int fr = lane & 15, kg = lane >> 4;
  f32x4 acc[4][4] = {};
  int sr = tid >> 1;
  int sc = (tid & 1) * 16;
  const short* Arow = A + (size_t)(bm + sr) * K + sc;
  int wrow = bn + sr;
  int wclamp = wrow < N ? wrow : 0;
  const float* Wrow_f = Wp + (size_t)wclamp * K + sc;
  for (int k0 = 0; k0 < K; k0 += 32) {
    s8v a0 = *(const s8v*)(Arow + k0);
    s8v a1 = *(const s8v*)(Arow + k0 + 8);
    s8v w0, w1;
    float4 f0 = *(const float4*)(Wrow_f + k0);
    float4 f1 = *(const float4*)(Wrow_f + k0 + 4);
    float4 f2 = *(const float4*)(Wrow_f + k0 + 8);
    float4 f3 = *(const float4*)(Wrow_f + k0 + 12);
    w0[0] = f2bf(f0.x); w0[1] = f2bf(f0.y); w0[2] = f2bf(f0.z); w0[3] = f2bf(f0.w);
    w0[4] = f2bf(f1.x); w0[5] = f2bf(f1.y); w0[6] = f2bf(f1.z); w0[7] = f2bf(f1.w);
    w1[0] = f2bf(f2.x); w1[1] = f2bf(f2.y); w1[2] = f2bf(f2.z); w1[3] = f2bf(f2.w);
    w1[4] = f2bf(f3.x); w1[5] = f2bf(f3.y); w1[6] = f2bf(f3.z); w1[7] = f2bf(f3.w);
    __syncthreads();
    *(s8v*)&As[sr][sc] = a0;
    *(s8v*)&As[sr][sc + 8] = a1;
    *(s8v*)&Ws[sr][sc] = w0;
    *(s8v*)&Ws[sr][sc + 8] = w1;
    __syncthreads();
    s8v af[4], bfv[4];
#pragma unroll
    for (int m = 0; m < 4; m++) af[m] = *(const s8v*)&As[wm + m * 16 + fr][kg * 8];
#pragma unroll
    for (int n = 0; n < 4; n++) bfv[n] = *(const s8v*)&Ws[wn + n * 16 + fr][kg * 8];
#pragma unroll
    for (int m = 0; m < 4; m++)
#pragma unroll
      for (int n = 0; n < 4; n++)
        acc[m][n] = __builtin_amdgcn_mfma_f32_16x16x32_bf16(af[m], bfv[n], acc[m][n], 0, 0, 0);
  }
  int rbase = bm + wm + kg * 4;
#pragma unroll
  for (int n = 0; n < 4; n++) {
    int col = bn + wn + n * 16 + fr;
    if (col >= N) continue;
    float bv = bias ? bias[col] : 0.0f;
    if (Vt != nullptr && col >= 1024) {
      int hh = (col - 1024) >> 6, dd = (col - 1024) & 63;
#pragma unroll
      for (int m = 0; m < 4; m++) {
        int row0 = rbase + m * 16;
        int bb = row0 >> 10, ll = row0 & 1023;
        short4 pk;
        pk.x = f2bf(acc[m][n][0] + bv);
        pk.y = f2bf(acc[m][n][1] + bv);
        pk.z = f2bf(acc[m][n][2] + bv);
        pk.w = f2bf(acc[m][n][3] + bv);
        *(short4*)&Vt[((((size_t)bb * NH + hh) * DH + dd) << 10) | ll] = pk;
      }
      continue;
    }
#pragma unroll
    for (int m = 0; m < 4; m++) {
#pragma unroll
      for (int r = 0; r < 4; r++) {
        int row = rbase + m * 16 + r;
        float v = act_apply(acc[m][n][r] + bv, act);
        if (OUTBF) Cb[(size_t)row * N + col] = f2bf(v);
        else C[(size_t)row * N + col] = v;
      }
    }
  }
}

// ---------------- MFMA flash attention (V pre-transposed, reg-prefetched K/V) ----------------
__global__ __launch_bounds__(256) void mha_kernel(
    const short* __restrict__ qkv, const short* __restrict__ vt,
    const float* __restrict__ phase, short* __restrict__ out) {
  __shared__ short sQ[64][72];
  __shared__ short sK[64][72];
  __shared__ short sVt[64][72];
  __shared__ short sP[64][72];
  __shared__ float sPh[Lseq];
  int bh = blockIdx.y;
  int b = bh >> 3, h = bh & 7;
  int q0 = blockIdx.x * 64;
  int tid = threadIdx.x;
  int lane = tid & 63, wid = tid >> 6;
  int fr = lane & 15, kg = lane >> 4;
  int wm = wid * 16;
  const short* vtb = vt + ((size_t)bh * DH) * Lseq;

  // per-thread staging coordinates (2 rows each of K and Vt)
  int srow0 = tid >> 3, srow1 = (tid + 256) >> 3;
  int sc8_0 = (tid & 7) * 8, sc8_1 = sc8_0;  // same (idx&7) for idx and idx+256
  const short* kbase = qkv + ((size_t)(b * Lseq) * 3 + 1) * D + h * DH;

  for (int j = tid; j < Lseq; j += 256) sPh[j] = phase[((size_t)(b * Lseq + j)) * NH + h];
  for (int idx = tid; idx < 512; idx += 256) {
    int row = idx >> 3, c8 = (idx & 7) * 8;
    *(s8v*)&sQ[row][c8] =
        *(const s8v*)(qkv + (((size_t)(b * Lseq + q0 + row)) * 3 + 0) * D + h * DH + c8);
  }

  // prefetch tile 0 K/V into registers
  s8v kr0, kr1, vr0, vr1;
  auto loadkv = [&](int k0) {
    kr0 = *(const s8v*)(kbase + (size_t)(k0 + srow0) * 3 * D + sc8_0);
    kr1 = *(const s8v*)(kbase + (size_t)(k0 + srow1) * 3 * D + sc8_1);
    vr0 = *(const s8v*)(vtb + (size_t)srow0 * Lseq + k0 + sc8_0);
    vr1 = *(const s8v*)(vtb + (size_t)srow1 * Lseq + k0 + sc8_1);
  };
  loadkv(0);
  __syncthreads();

  float phq[4];
#pragma unroll
  for (int r = 0; r < 4; r++) phq[r] = sPh[q0 + wm + kg * 4 + r];

  float mrow[4] = {-1e30f, -1e30f, -1e30f, -1e30f};
  float lrow[4] = {0.f, 0.f, 0.f, 0.f};
  f32x4 o[4] = {};

  for (int kt = 0; kt < Lseq / 64; kt++) {
    int k0 = kt * 64;
    __syncthreads();
    *(s8v*)&sK[srow0][sc8_0] = kr0;
    *(s8v*)&sK[srow1][sc8_1] = kr1;
    *(s8v*)&sVt[srow0][sc8_0] = vr0;
    *(s8v*)&sVt[srow1][sc8_1] = vr1;
    __syncthreads();
    if (kt + 1 < Lseq / 64) loadkv(k0 + 64);   // latency hides under compute

    s8v qa0 = *(const s8v*)&sQ[wm + fr][kg * 8];
    s8v qa1 = *(const s8v*)&sQ[wm + fr][32 + kg * 8];
    f32x4 sacc[4];
#pragma unroll
    for (int n = 0; n < 4; n++) {
      f32x4 z = {};
      s8v kb0 = *(const s8v*)&sK[n * 16 + fr][kg * 8];
      s8v kb1 = *(const s8v*)&sK[n * 16 + fr][32 + kg * 8];
      z = __builtin_amdgcn_mfma_f32_16x16x32_bf16(qa0, kb0, z, 0, 0, 0);
      z = __builtin_amdgcn_mfma_f32_16x16x32_bf16(qa1, kb1, z, 0, 0, 0);
      sacc[n] = z;
    }
    float sv[4][4];
#pragma unroll
    for (int n = 0; n < 4; n++) {
      float phk = sPh[k0 + n * 16 + fr];
#pragma unroll
      for (int r = 0; r < 4; r++) {
        float dp = phq[r] - phk;
        sv[n][r] = sacc[n][r] * 0.125f - dp * dp;
      }
    }
    float mnew[4], alpha[4];
#pragma unroll
    for (int r = 0; r < 4; r++) {
      float mx = fmaxf(fmaxf(sv[0][r], sv[1][r]), fmaxf(sv[2][r], sv[3][r]));
#pragma unroll
      for (int off = 1; off < 16; off <<= 1) mx = fmaxf(mx, __shfl_xor(mx, off, 64));
      mnew[r] = fmaxf(mrow[r], mx);
      alpha[r] = __expf(mrow[r] - mnew[r]);
      mrow[r] = mnew[r];
    }
    float rs[4] = {0.f, 0.f, 0.f, 0.f};
#pragma unroll
    for (int n = 0; n < 4; n++) {
#pragma unroll
      for (int r = 0; r < 4; r++) {
        float p = __expf(sv[n][r] - mnew[r]);
        rs[r] += p;
        sP[wm + kg * 4 + r][n * 16 + fr] = f2bf(p);
      }
    }
#pragma unroll
    for (int r = 0; r < 4; r++) {
#pragma unroll
      for (int off = 1; off < 16; off <<= 1) rs[r] += __shfl_xor(rs[r], off, 64);
      lrow[r] = lrow[r] * alpha[r] + rs[r];
    }
#pragma unroll
    for (int df = 0; df < 4; df++) {
      o[df][0] *= alpha[0]; o[df][1] *= alpha[1];
      o[df][2] *= alpha[2]; o[df][3] *= alpha[3];
    }
    s8v pa0 = *(const s8v*)&sP[wm + fr][kg * 8];
    s8v pa1 = *(const s8v*)&sP[wm + fr][32 + kg * 8];
#pragma unroll
    for (int df = 0; df < 4; df++) {
      int d = df * 16 + fr;
      s8v vb0 = *(const s8v*)&sVt[d][kg * 8];
      s8v vb1 = *(const s8v*)&sVt[d][32 + kg * 8];
      o[df] = __builtin_amdgcn_mfma_f32_16x16x32_bf16(pa0, vb0, o[df], 0, 0, 0);
      o[df] = __builtin_amdgcn_mfma_f32_16x16x32_bf16(pa1, vb1, o[df], 0, 0, 0);
    }
  }
  float inv[4];
#pragma unroll
  for (int r = 0; r < 4; r++) inv[r] = 1.0f / lrow[r];
#pragma unroll
  for (int df = 0; df < 4; df++) {
#pragma unroll
    for (int r = 0; r < 4; r++) {
      int row = q0 + wm + kg * 4 + r;
      out[((size_t)(b * Lseq + row)) * D + h * DH + df * 16 + fr] = f2bf(o[df][r] * inv[r]);
    }
  }
}

// ---------------- fused boundary gate + xg = bf16(x * gate) ----------------
__global__ __launch_bounds__(128) void gatexg_kernel(
    const float* __restrict__ tb, const float* __restrict__ w2,
    const float* __restrict__ b2, const float* __restrict__ x,
    float* __restrict__ gate, short* __restrict__ xg) {
  __shared__ float sred[2];
  int tok = blockIdx.x, t = threadIdx.x;   // 128 threads = 2 waves
  const float* row = tb + (size_t)tok * D;
  float acc = row[t] * w2[t] + row[t + 128] * w2[t + 128] +
              row[t + 256] * w2[t + 256] + row[t + 384] * w2[t + 384];
#pragma unroll
  for (int off = 32; off > 0; off >>= 1) acc += __shfl_xor(acc, off, 64);
  if ((t & 63) == 0) sred[t >> 6] = acc;
  __syncthreads();
  float g = 1.0f / (1.0f + expf(-(sred[0] + sred[1] + b2[0])));
  if (t == 0) gate[tok] = g;
  float4 v = *(const float4*)(x + (size_t)tok * D + t * 4);
  short4 o = make_short4(f2bf(v.x * g), f2bf(v.y * g), f2bf(v.z * g), f2bf(v.w * g));
  *(short4*)(xg + (size_t)tok * D + t * 4) = o;
}

extern "C" void kernel_launch(void* const* d_in, const int* in_sizes, int n_in,
                              void* d_out, int out_size, void* d_ws, size_t ws_size,
                              hipStream_t stream) {
  const int* ids = (const int*)d_in[0];
  const float* emb = (const float*)d_in[1];
  const float* pos = (const float*)d_in[2];
  const float* rg_w = (const float*)d_in[3];
  const float* rg_b = (const float*)d_in[4];
  const float* qkv_w = (const float*)d_in[5];
  const float* qkv_b = (const float*)d_in[6];
  const float* out_w = (const float*)d_in[7];
  const float* out_b = (const float*)d_in[8];
  const float* ph_w = (const float*)d_in[9];
  const float* ph_b = (const float*)d_in[10];
  const float* ff1_w = (const float*)d_in[11];
  const float* ff1_b = (const float*)d_in[12];
  const float* ff2_w = (const float*)d_in[13];
  const float* ff2_b = (const float*)d_in[14];
  const float* n1_s = (const float*)d_in[15];
  const float* n1_b = (const float*)d_in[16];
  const float* n2_s = (const float*)d_in[17];
  const float* n2_b = (const float*)d_in[18];
  const float* bw1 = (const float*)d_in[19];
  const float* bb1 = (const float*)d_in[20];
  const float* bw2 = (const float*)d_in[21];
  const float* bb2 = (const float*)d_in[22];
  const float* head_w = (const float*)d_in[23];

  char* w = (char*)d_ws;
  float* x      = (float*)(w + 0);           //  8.39 MB
  float* ao     = (float*)(w + 8388608);     //  8.39 MB (bnd tanh-buf; first 4.2 MB doubles as y_bf)
  short* y_bf   = (short*)(w + 8388608);     //  4.19 MB (residual-add input, bf16)
  float* phase  = (float*)(w + 16777216);    //  0.13 MB
  short* h_bf   = (short*)(w + 16908288);    //  4.19 MB
  short* ao_bf  = (short*)(w + 21102592);    //  4.19 MB
  short* x_bf   = (short*)(w + 25296896);    //  4.19 MB
  short* ff_bf  = (short*)(w + 29491200);    // 16.78 MB
  short* xg_bf  = (short*)(w + 46268416);    //  4.19 MB
  short* qkv_bf = (short*)(w + 50462720);    // 12.58 MB
  short* vt_bf  = (short*)(w + 63045632);    //  4.19 MB
  short* wqkv   = (short*)(w + 67239936);    //  9.44 MB
  short* wout   = (short*)(w + 76677120);    //  3.15 MB
  short* wff1   = (short*)(w + 79822848);    // 12.58 MB
  short* wff2   = (short*)(w + 92405760);    // 12.58 MB
  short* wbnd   = (short*)(w + 104988672);   //  0.52 MB
  short* whead  = (short*)(w + 105512960);   // 30.72 MB
  const size_t WS_FULL = 136232960;

  float* outf   = (float*)d_out;
  float* logits = outf;
  float* gate   = outf + 122880000;
  float* rg_out = outf + 122884096;

  bool fast = ws_size >= WS_FULL;

  if (fast) {
    f2bf6_kernel<<<(34496512 / 8 + 255) / 256, 256, 0, stream>>>(
        qkv_w, wqkv, 4718592, out_w, wout, 1572864, ff1_w, wff1, 6291456,
        ff2_w, wff2, 6291456, bw1, wbnd, 262144, head_w, whead, 15360000);
  }

  embed_kernel<<<BL, 128, 0, stream>>>(ids, emb, pos, x);

  for (int l = 0; l < NL; l++) {
    rg_ln_kernel<<<BL, 256, 0, stream>>>(
        x, rg_w + (size_t)l * 4 * D, rg_b + l * 4, n1_s + l * D, n1_b + l * D,
        ph_w + (size_t)l * NH * D, ph_b + l * NH,
        h_bf, phase, (l == NL - 1) ? rg_out : nullptr);
    if (fast)
      gemm64_kernel<true><<<dim3(12, 64), 256, 0, stream>>>(
          h_bf, wqkv + (size_t)l * 1536 * D, qkv_b + l * 1536, nullptr, qkv_bf, vt_bf,
          BL, 1536, D, 0);
    else
      gemm_conv_kernel<true><<<dim3(12, 32), 256, 0, stream>>>(
          h_bf, qkv_w + (size_t)l * 1536 * D, qkv_b + l * 1536, nullptr, qkv_bf, vt_bf,
          BL, 1536, D, 0);
    mha_kernel<<<dim3(Lseq / 64, Bsz * NH), 256, 0, stream>>>(qkv_bf, vt_bf, phase, ao_bf);
    if (fast)
      gemm64_kernel<true><<<dim3(4, 64), 256, 0, stream>>>(
          ao_bf, wout + (size_t)l * D * D, out_b + l * D, nullptr, y_bf, nullptr, BL, D, D, 0);
    else
      gemm_conv_kernel<true><<<dim3(4, 32), 256, 0, stream>>>(
          ao_bf, out_w + (size_t)l * D * D, out_b + l * D, nullptr, y_bf, nullptr, BL, D, D, 0);
    residual_ln_kernel<<<BL, 256, 0, stream>>>(x, y_bf, n1_s + l * D, n1_b + l * D, x_bf);
    if (fast)
      gemm64_kernel<true><<<dim3(16, 64), 256, 0, stream>>>(
          x_bf, wff1 + (size_t)l * 2048 * D, ff1_b + l * 2048, nullptr, ff_bf, nullptr,
          BL, 2048, D, 1);
    else
      gemm_conv_kernel<true><<<dim3(16, 32), 256, 0, stream>>>(
          x_bf, ff1_w + (size_t)l * 2048 * D, ff1_b + l * 2048, nullptr, ff_bf, nullptr,
          BL, 2048, D, 1);
    if (fast)
      gemm64_kernel<true><<<dim3(4, 64), 256, 0, stream>>>(
          ff_bf, wff2 + (size_t)l * D * 2048, ff2_b + l * D, nullptr, y_bf, nullptr,
          BL, D, 2048, 0);
    else
      gemm_conv_kernel<true><<<dim3(4, 32), 256, 0, stream>>>(
          ff_bf, ff2_w + (size_t)l * D * 2048, ff2_b + l * D, nullptr, y_bf, nullptr,
          BL, D, 2048, 0);
    residual_ln_kernel<<<BL, 256, 0, stream>>>(x, y_bf, n2_s + l * D, n2_b + l * D, x_bf);
  }

  if (fast)
    gemm64_kernel<false><<<dim3(4, 64), 256, 0, stream>>>(
        x_bf, wbnd, bb1, ao, nullptr, nullptr, BL, D, D, 2);
  else
    gemm_conv_kernel<false><<<dim3(4, 32), 256, 0, stream>>>(
        x_bf, bw1, bb1, ao, nullptr, nullptr, BL, D, D, 2);
  gatexg_kernel<<<BL, 128, 0, stream>>>(ao, bw2, bb2, x, gate, xg_bf);
  if (fast)
    gemm128_kernel<1, true><<<dim3(32, 235), 256, 0, stream>>>(
        xg_bf, whead, nullptr, logits, BL, Vocab, D, 0);
  else
    gemm_conv_kernel<false><<<dim3(235, 32), 256, 0, stream>>>(
        xg_bf, head_w, nullptr, logits, nullptr, nullptr, BL, Vocab, D, 0);
}

// Round 16
// 1132.022 us; speedup vs baseline: 1.1727x; 1.0191x over previous
//
#include <hip/hip_runtime.h>
#include <math.h>

#define D 512
#define NH 8
#define DH 64
#define NL 6
#define Bsz 4
#define Lseq 1024
#define BL 4096          // B*L tokens
#define Vocab 30000
#define EPS 1e-5f

typedef __attribute__((ext_vector_type(8))) short s8v;   // 8 bf16 (4 VGPRs)
typedef __attribute__((ext_vector_type(4))) float f32x4; // MFMA accumulator
typedef __attribute__((ext_vector_type(4))) float f4v;   // clang vector (NT-store OK)

__device__ __forceinline__ float sigmoidf_(float x) { return 1.0f / (1.0f + expf(-x)); }

__device__ __forceinline__ short f2bf(float f) {  // fp32 -> bf16 bits, RNE
  union { float f; unsigned u; } v; v.f = f;
  return (short)((v.u + 0x7FFFu + ((v.u >> 16) & 1u)) >> 16);
}
__device__ __forceinline__ float bf2f(short s) {
  union { unsigned u; float f; } v; v.u = ((unsigned)(unsigned short)s) << 16;
  return v.f;
}

// async global->LDS, 16B per lane. LDS dest is wave-uniform base; HW adds lane*16.
__device__ __forceinline__ void gload16(const void* g, void* l) {
  __builtin_amdgcn_global_load_lds(
      (const __attribute__((address_space(1))) void*)g,
      (__attribute__((address_space(3))) void*)l, 16, 0, 0);
}

__device__ __forceinline__ float act_apply(float v, int act) {
  if (act == 1) return 0.5f * v * (1.0f + erff(v * 0.7071067811865475f));
  if (act == 2) return tanhf(v);
  return v;
}

// ---------------- fp32 -> bf16 bulk convert: 6 segments in one launch ----------------
__global__ void f2bf6_kernel(
    const float* __restrict__ s0, short* __restrict__ d0, int n0,
    const float* __restrict__ s1, short* __restrict__ d1, int n1,
    const float* __restrict__ s2, short* __restrict__ d2, int n2,
    const float* __restrict__ s3, short* __restrict__ d3, int n3,
    const float* __restrict__ s4, short* __restrict__ d4, int n4,
    const float* __restrict__ s5, short* __restrict__ d5, int n5) {
  long i = ((long)blockIdx.x * 256 + threadIdx.x) * 8;
  const float* s; short* d;
  if (i < n0) { s = s0; d = d0; }
  else {
    i -= n0;
    if (i < n1) { s = s1; d = d1; }
    else {
      i -= n1;
      if (i < n2) { s = s2; d = d2; }
      else {
        i -= n2;
        if (i < n3) { s = s3; d = d3; }
        else {
          i -= n3;
          if (i < n4) { s = s4; d = d4; }
          else { i -= n4; if (i >= n5) return; s = s5; d = d5; }
        }
      }
    }
  }
  float4 a = *(const float4*)(s + i);
  float4 b = *(const float4*)(s + i + 4);
  s8v o;
  o[0] = f2bf(a.x); o[1] = f2bf(a.y); o[2] = f2bf(a.z); o[3] = f2bf(a.w);
  o[4] = f2bf(b.x); o[5] = f2bf(b.y); o[6] = f2bf(b.z); o[7] = f2bf(b.w);
  *(s8v*)(d + i) = o;
}

// ---------------- embed + pos ----------------
__global__ void embed_kernel(const int* __restrict__ ids, const float* __restrict__ emb,
                             const float* __restrict__ pos, float* __restrict__ x) {
  int tok = blockIdx.x;
  int l = tok & (Lseq - 1);
  int id = ids[tok];
  const float4* e = (const float4*)(emb + (size_t)id * D);
  const float4* p = (const float4*)(pos + (size_t)l * D);
  float4* o = (float4*)(x + (size_t)tok * D);
  float4 a = e[threadIdx.x], b = p[threadIdx.x];
  o[threadIdx.x] = make_float4(a.x + b.x, a.y + b.y, a.z + b.z, a.w + b.w);
}

// ---- shared body: rg gates + modulate + LN1 -> h, phase (input x0,x1 per thread) ----
__device__ __forceinline__ void rg_body(
    float x0, float x1, int tok, int t, int wid, int lane,
    const float* __restrict__ rgw, const float* __restrict__ rgb,
    const float* __restrict__ sc, const float* __restrict__ bi,
    const float* __restrict__ pw, const float* __restrict__ pb,
    short* __restrict__ h, float* __restrict__ phase, float* __restrict__ rg_out,
    float (*smg)[4], float (*sms)[2], float* smh) {
  float p0 = x0 * rgw[t]        + x1 * rgw[t + 256];
  float p1 = x0 * rgw[512 + t]  + x1 * rgw[512 + t + 256];
  float p2 = x0 * rgw[1024 + t] + x1 * rgw[1024 + t + 256];
  float p3 = x0 * rgw[1536 + t] + x1 * rgw[1536 + t + 256];
#pragma unroll
  for (int off = 32; off > 0; off >>= 1) {
    p0 += __shfl_xor(p0, off, 64);
    p1 += __shfl_xor(p1, off, 64);
    p2 += __shfl_xor(p2, off, 64);
    p3 += __shfl_xor(p3, off, 64);
  }
  if (lane == 0) { smg[wid][0] = p0; smg[wid][1] = p1; smg[wid][2] = p2; smg[wid][3] = p3; }
  __syncthreads();
  float g0 = sigmoidf_(smg[0][0] + smg[1][0] + smg[2][0] + smg[3][0] + rgb[0]);
  float g1 = sigmoidf_(smg[0][1] + smg[1][1] + smg[2][1] + smg[3][1] + rgb[1]);
  float g2 = sigmoidf_(smg[0][2] + smg[1][2] + smg[2][2] + smg[3][2] + rgb[2]);
  float g3 = sigmoidf_(smg[0][3] + smg[1][3] + smg[2][3] + smg[3][3] + rgb[3]);
  if (rg_out != nullptr && t == 0) {
    float* ro = rg_out + (size_t)tok * 4;
    ro[0] = g0; ro[1] = g1; ro[2] = g2; ro[3] = g3;
  }
  float mod = 1.0f + 0.25f * (g0 + g1 + g2 + g3);
  float m0 = x0 * mod, m1 = x1 * mod;
  float s = m0 + m1, q = m0 * m0 + m1 * m1;
#pragma unroll
  for (int off = 32; off > 0; off >>= 1) {
    s += __shfl_xor(s, off, 64);
    q += __shfl_xor(q, off, 64);
  }
  if (lane == 0) { sms[wid][0] = s; sms[wid][1] = q; }
  __syncthreads();
  float S = sms[0][0] + sms[1][0] + sms[2][0] + sms[3][0];
  float Q = sms[0][1] + sms[1][1] + sms[2][1] + sms[3][1];
  float mean = S * (1.0f / D);
  float var = Q * (1.0f / D) - mean * mean;
  float rstd = rsqrtf(var + EPS);
  float o0 = (m0 - mean) * rstd * sc[t] + bi[t];
  float o1 = (m1 - mean) * rstd * sc[t + 256] + bi[t + 256];
  h[(size_t)tok * D + t] = f2bf(o0);
  h[(size_t)tok * D + t + 256] = f2bf(o1);
  smh[t] = o0;
  smh[t + 256] = o1;
  __syncthreads();
  // phase: each wave reduces 2 heads from LDS-staged h
  const float4* hv = (const float4*)&smh[lane * 8];
  float4 a0 = hv[0], a1 = hv[1];
  float ph[2];
#pragma unroll
  for (int j = 0; j < 2; j++) {
    int hh = wid * 2 + j;
    const float4* wv = (const float4*)&pw[hh * D + lane * 8];
    float4 b0 = wv[0], b1 = wv[1];
    float acc = a0.x * b0.x + a0.y * b0.y + a0.z * b0.z + a0.w * b0.w +
                a1.x * b1.x + a1.y * b1.y + a1.z * b1.z + a1.w * b1.w;
#pragma unroll
    for (int off = 32; off > 0; off >>= 1) acc += __shfl_xor(acc, off, 64);
    ph[j] = acc;
  }
  if (lane == 0) {
    int hh = wid * 2;
    phase[(size_t)tok * NH + hh] = ph[0] + pb[hh];
    phase[(size_t)tok * NH + hh + 1] = ph[1] + pb[hh + 1];
  }
}

// ---------- rg gate + modulate + LN1 -> h, phase (reads x directly) ----------
__global__ __launch_bounds__(256) void rg_ln_kernel(
    const float* __restrict__ x, const float* __restrict__ rgw, const float* __restrict__ rgb,
    const float* __restrict__ sc, const float* __restrict__ bi,
    const float* __restrict__ pw, const float* __restrict__ pb,
    short* __restrict__ h, float* __restrict__ phase, float* __restrict__ rg_out) {
  __shared__ float smg[4][4];
  __shared__ float sms[4][2];
  __shared__ float smh[512];
  int tok = blockIdx.x, t = threadIdx.x, wid = t >> 6, lane = t & 63;
  const float* xr = x + (size_t)tok * D;
  rg_body(xr[t], xr[t + 256], tok, t, wid, lane, rgw, rgb, sc, bi, pw, pb,
          h, phase, rg_out, smg, sms, smh);
}

// -------- fused: residual+LN2 (layer l) -> x, then rg/LN1/phase (layer l+1) --------
__global__ __launch_bounds__(256) void resrg_kernel(
    float* __restrict__ x, const short* __restrict__ y,
    const float* __restrict__ sc2, const float* __restrict__ bi2,
    const float* __restrict__ rgw, const float* __restrict__ rgb,
    const float* __restrict__ sc1, const float* __restrict__ bi1,
    const float* __restrict__ pw, const float* __restrict__ pb,
    short* __restrict__ h, float* __restrict__ phase, float* __restrict__ rg_out) {
  __shared__ float smg[4][4];
  __shared__ float sms[4][2];
  __shared__ float smh[512];
  int tok = blockIdx.x, t = threadIdx.x, wid = t >> 6, lane = t & 63;
  float v0 = x[(size_t)tok * D + t] + bf2f(y[(size_t)tok * D + t]);
  float v1 = x[(size_t)tok * D + t + 256] + bf2f(y[(size_t)tok * D + t + 256]);
  float s = v0 + v1, q = v0 * v0 + v1 * v1;
#pragma unroll
  for (int off = 32; off > 0; off >>= 1) {
    s += __shfl_xor(s, off, 64);
    q += __shfl_xor(q, off, 64);
  }
  if (lane == 0) { sms[wid][0] = s; sms[wid][1] = q; }
  __syncthreads();
  float S = sms[0][0] + sms[1][0] + sms[2][0] + sms[3][0];
  float Q = sms[0][1] + sms[1][1] + sms[2][1] + sms[3][1];
  float mean = S * (1.0f / D);
  float var = Q * (1.0f / D) - mean * mean;
  float rstd = rsqrtf(var + EPS);
  float o0 = (v0 - mean) * rstd * sc2[t] + bi2[t];
  float o1 = (v1 - mean) * rstd * sc2[t + 256] + bi2[t + 256];
  x[(size_t)tok * D + t] = o0;        // residual stream for next res_ln1
  x[(size_t)tok * D + t + 256] = o1;  // (x_bf not needed until after last layer)
  __syncthreads();                    // sms reused inside rg_body
  rg_body(o0, o1, tok, t, wid, lane, rgw, rgb, sc1, bi1, pw, pb,
          h, phase, rg_out, smg, sms, smh);
}

// ---------------- residual + layernorm (x fp32 in-place; y is bf16) ----------------
__global__ __launch_bounds__(256) void residual_ln_kernel(
    float* __restrict__ x, const short* __restrict__ y,
    const float* __restrict__ sc, const float* __restrict__ bi,
    short* __restrict__ xb) {
  __shared__ float sms[4][2];
  int tok = blockIdx.x, t = threadIdx.x, wid = t >> 6, lane = t & 63;
  float v0 = x[(size_t)tok * D + t] + bf2f(y[(size_t)tok * D + t]);
  float v1 = x[(size_t)tok * D + t + 256] + bf2f(y[(size_t)tok * D + t + 256]);
  float s = v0 + v1, q = v0 * v0 + v1 * v1;
#pragma unroll
  for (int off = 32; off > 0; off >>= 1) {
    s += __shfl_xor(s, off, 64);
    q += __shfl_xor(q, off, 64);
  }
  if (lane == 0) { sms[wid][0] = s; sms[wid][1] = q; }
  __syncthreads();
  float S = sms[0][0] + sms[1][0] + sms[2][0] + sms[3][0];
  float Q = sms[0][1] + sms[1][1] + sms[2][1] + sms[3][1];
  float mean = S * (1.0f / D);
  float var = Q * (1.0f / D) - mean * mean;
  float rstd = rsqrtf(var + EPS);
  float o0 = (v0 - mean) * rstd * sc[t] + bi[t];
  float o1 = (v1 - mean) * rstd * sc[t + 256] + bi[t + 256];
  x[(size_t)tok * D + t] = o0;
  x[(size_t)tok * D + t + 256] = o1;
  xb[(size_t)tok * D + t] = f2bf(o0);
  xb[(size_t)tok * D + t + 256] = f2bf(o1);
}

// ================= 2-phase dbuf GEMM, BM=128 (head only) =================
template <int MODE, bool SWAP>
__global__ __launch_bounds__(256) void gemm128_kernel(
    const short* __restrict__ A, const short* __restrict__ W,
    const float* __restrict__ bias, float* __restrict__ C,
    int M, int N, int K, int act) {
  __shared__ char smem[32768];
  short* AsF = (short*)smem;
  short* WsF = (short*)(smem + 16384);
  int tid = threadIdx.x;
  int bn, bm;
  if (SWAP) { bm = blockIdx.x * 128; bn = blockIdx.y * 128; }
  else      { bn = blockIdx.x * 128; bm = blockIdx.y * 128; }
  int wid = tid >> 6, lane = tid & 63;
  int wm = (wid >> 1) * 64, wn = (wid & 1) * 64;
  int fr = lane & 15, kg = lane >> 4;
  f32x4 acc[4][4] = {};
  int srow = 32 * wid + (lane >> 2);
  int scol = (lane & 3) * 8;
  const short* Ag0 = A + (size_t)(bm + srow) * K + scol;
  const short* Ag1 = Ag0 + (size_t)16 * K;
  int wr0 = bn + srow;       if (wr0 >= N) wr0 = N - 1;
  int wr1 = bn + srow + 16;  if (wr1 >= N) wr1 = N - 1;
  const short* Wg0 = W + (size_t)wr0 * K + scol;
  const short* Wg1 = W + (size_t)wr1 * K + scol;
  auto stage = [&](int buf, int k0) {
    gload16(Ag0 + k0, AsF + buf * 4096 + (32 * wid) * 32);
    gload16(Ag1 + k0, AsF + buf * 4096 + (32 * wid + 16) * 32);
    gload16(Wg0 + k0, WsF + buf * 4096 + (32 * wid) * 32);
    gload16(Wg1 + k0, WsF + buf * 4096 + (32 * wid + 16) * 32);
  };
  stage(0, 0);
  __syncthreads();
  int nt = K / 32, cur = 0;
  for (int t = 0; t < nt; ++t) {
    if (t + 1 < nt) stage(cur ^ 1, (t + 1) * 32);
    const short* ab = AsF + cur * 4096;
    const short* wb = WsF + cur * 4096;
    s8v af[4], bfv[4];
#pragma unroll
    for (int m = 0; m < 4; m++) af[m] = *(const s8v*)(ab + (wm + m * 16 + fr) * 32 + kg * 8);
#pragma unroll
    for (int n = 0; n < 4; n++) bfv[n] = *(const s8v*)(wb + (wn + n * 16 + fr) * 32 + kg * 8);
#pragma unroll
    for (int m = 0; m < 4; m++)
#pragma unroll
      for (int n = 0; n < 4; n++)
        acc[m][n] = __builtin_amdgcn_mfma_f32_16x16x32_bf16(af[m], bfv[n], acc[m][n], 0, 0, 0);
    __syncthreads();
    cur ^= 1;
  }
  float* eps = (float*)smem;
#pragma unroll
  for (int c = 0; c < 2; ++c) {
    __syncthreads();
    if ((wid >> 1) == c) {
#pragma unroll
      for (int n = 0; n < 4; n++) {
        int col = wn + n * 16 + fr;
        int gcol = bn + col;
        float bv = bias ? bias[gcol < N ? gcol : N - 1] : 0.0f;
#pragma unroll
        for (int m = 0; m < 4; m++)
#pragma unroll
          for (int r = 0; r < 4; r++)
            eps[(m * 16 + kg * 4 + r) * 128 + col] = act_apply(acc[m][n][r] + bv, act);
      }
    }
    __syncthreads();
#pragma unroll
    for (int i = 0; i < 8; i++) {
      int idx = tid + i * 256;
      int rl = idx >> 5;
      int c4 = (idx & 31) * 4;
      int row = bm + c * 64 + rl;
      int col = bn + c4;
      f4v v = *(f4v*)&eps[rl * 128 + c4];
      float* dst = C + (size_t)row * N + col;
      if (col + 3 < N) {
        if (MODE == 1) __builtin_nontemporal_store(v, (f4v*)dst);
        else *(f4v*)dst = v;
      } else {
        for (int j = 0; j < 4; j++)
          if (col + j < N) {
            if (MODE == 1) __builtin_nontemporal_store(v[j], dst + j);
            else dst[j] = v[j];
          }
      }
    }
  }
}

// ================= 2-phase dbuf GEMM, BM=64 =================
template <bool OUTBF>
__global__ __launch_bounds__(256) void gemm64_kernel(
    const short* __restrict__ A, const short* __restrict__ W,
    const float* __restrict__ bias, float* __restrict__ C, short* __restrict__ Cb,
    short* __restrict__ Vt, int M, int N, int K, int act) {
  __shared__ char smem[24576];
  short* AsF = (short*)smem;
  short* WsF = (short*)(smem + 8192);
  int tid = threadIdx.x;
  int bn = blockIdx.x * 128, bm = blockIdx.y * 64;
  int wid = tid >> 6, lane = tid & 63;
  int fr = lane & 15, kg = lane >> 4;
  f32x4 acc[4][2] = {};
  int l4 = lane >> 2;
  int scol = (lane & 3) * 8;
  const short* Ag0 = A + (size_t)(bm + 16 * wid + l4) * K + scol;
  int wr0 = bn + 32 * wid + l4;       if (wr0 >= N) wr0 = N - 1;
  int wr1 = bn + 32 * wid + 16 + l4;  if (wr1 >= N) wr1 = N - 1;
  const short* Wg0 = W + (size_t)wr0 * K + scol;
  const short* Wg1 = W + (size_t)wr1 * K + scol;
  auto stage = [&](int buf, int k0) {
    gload16(Ag0 + k0, AsF + buf * 2048 + (16 * wid) * 32);
    gload16(Wg0 + k0, WsF + buf * 4096 + (32 * wid) * 32);
    gload16(Wg1 + k0, WsF + buf * 4096 + (32 * wid + 16) * 32);
  };
  stage(0, 0);
  __syncthreads();
  int nt = K / 32, cur = 0;
  for (int t = 0; t < nt; ++t) {
    if (t + 1 < nt) stage(cur ^ 1, (t + 1) * 32);
    const short* ab = AsF + cur * 2048;
    const short* wb = WsF + cur * 4096;
    s8v af[4], bfv[2];
#pragma unroll
    for (int m = 0; m < 4; m++) af[m] = *(const s8v*)(ab + (m * 16 + fr) * 32 + kg * 8);
#pragma unroll
    for (int n = 0; n < 2; n++) bfv[n] = *(const s8v*)(wb + (wid * 32 + n * 16 + fr) * 32 + kg * 8);
#pragma unroll
    for (int m = 0; m < 4; m++)
#pragma unroll
      for (int n = 0; n < 2; n++)
        acc[m][n] = __builtin_amdgcn_mfma_f32_16x16x32_bf16(af[m], bfv[n], acc[m][n], 0, 0, 0);
    __syncthreads();
    cur ^= 1;
  }
  int rbase = bm + kg * 4;
  if (Vt != nullptr && bn >= 1024) {
#pragma unroll
    for (int n = 0; n < 2; n++) {
      int col = bn + wid * 32 + n * 16 + fr;
      float bv = bias ? bias[col] : 0.0f;
      int hh = (col - 1024) >> 6, dd = (col - 1024) & 63;
#pragma unroll
      for (int m = 0; m < 4; m++) {
        int row0 = rbase + m * 16;
        int bb = row0 >> 10, ll = row0 & 1023;
        short4 pk;
        pk.x = f2bf(acc[m][n][0] + bv);
        pk.y = f2bf(acc[m][n][1] + bv);
        pk.z = f2bf(acc[m][n][2] + bv);
        pk.w = f2bf(acc[m][n][3] + bv);
        *(short4*)&Vt[((((size_t)bb * NH + hh) * DH + dd) << 10) | ll] = pk;
      }
    }
    return;
  }
  if (OUTBF) {
    short* eph = (short*)smem;
    __syncthreads();
#pragma unroll
    for (int n = 0; n < 2; n++) {
      int col = wid * 32 + n * 16 + fr;
      float bv = bias ? bias[bn + col] : 0.0f;
#pragma unroll
      for (int m = 0; m < 4; m++)
#pragma unroll
        for (int r = 0; r < 4; r++)
          eph[(kg * 4 + m * 16 + r) * 128 + col] = f2bf(act_apply(acc[m][n][r] + bv, act));
    }
    __syncthreads();
#pragma unroll
    for (int i = 0; i < 4; i++) {
      int idx = tid + i * 256;
      int rl = idx >> 4;
      int c8 = (idx & 15) * 8;
      *(s8v*)&Cb[(size_t)(bm + rl) * N + bn + c8] = *(s8v*)&eph[rl * 128 + c8];
    }
  } else {
#pragma unroll
    for (int n = 0; n < 2; n++) {
      int col = bn + wid * 32 + n * 16 + fr;
      if (col >= N) continue;
      float bv = bias ? bias[col] : 0.0f;
#pragma unroll
      for (int m = 0; m < 4; m++)
#pragma unroll
        for (int r = 0; r < 4; r++)
          C[(size_t)(rbase + m * 16 + r) * N + col] = act_apply(acc[m][n][r] + bv, act);
    }
  }
}

// ---------------- fallback GEMM (fp32 weights converted in staging) ----------------
template <bool OUTBF>
__global__ __launch_bounds__(256) void gemm_conv_kernel(
    const short* __restrict__ A, const float* __restrict__ Wp,
    const float* __restrict__ bias, float* __restrict__ C, short* __restrict__ Cb,
    short* __restrict__ Vt, int M, int N, int K, int act) {
  __shared__ short As[128][40];
  __shared__ short Ws[128][40];
  int tid = threadIdx.x;
  int bn = blockIdx.x * 128, bm = blockIdx.y * 128;
  int wid = tid >> 6, lane = tid & 63;
  int wm = (wid >> 1) * 64, wn = (wid & 1) * 64;
  int fr = lane & 15, kg = lane >> 4;
  f32x4 acc[4][4] = {};
  int sr = tid >> 1;
  int sc = (tid & 1) * 16;
  const short* Arow = A + (size_t)(bm + sr) * K + sc;
  int wrow = bn + sr;
  int wclamp = wrow < N ? wrow : 0;
  const float* Wrow_f = Wp + (size_t)wclamp * K + sc;
  for (int k0 = 0; k0 < K; k0 += 32) {
    s8v a0 = *(const s8v*)(Arow + k0);
    s8v a1 = *(const s8v*)(Arow + k0 + 8);
    s8v w0, w1;
    float4 f0 = *(const float4*)(Wrow_f + k0);
    float4 f1 = *(const float4*)(Wrow_f + k0 + 4);
    float4 f2 = *(const float4*)(Wrow_f + k0 + 8);
    float4 f3 = *(const float4*)(Wrow_f + k0 + 12);
    w0[0] = f2bf(f0.x); w0[1] = f2bf(f0.y); w0[2] = f2bf(f0.z); w0[3] = f2bf(f0.w);
    w0[4] = f2bf(f1.x); w0[5] = f2bf(f1.y); w0[6] = f2bf(f1.z); w0[7] = f2bf(f1.w);
    w1[0] = f2bf(f2.x); w1[1] = f2bf(f2.y); w1[2] = f2bf(f2.z); w1[3] = f2bf(f2.w);
    w1[4] = f2bf(f3.x); w1[5] = f2bf(f3.y); w1[6] = f2bf(f3.z); w1[7] = f2bf(f3.w);
    __syncthreads();
    *(s8v*)&As[sr][sc] = a0;
    *(s8v*)&As[sr][sc + 8] = a1;
    *(s8v*)&Ws[sr][sc] = w0;
    *(s8v*)&Ws[sr][sc + 8] = w1;
    __syncthreads();
    s8v af[4], bfv[4];
#pragma unroll
    for (int m = 0; m < 4; m++) af[m] = *(const s8v*)&As[wm + m * 16 + fr][kg * 8];
#pragma unroll
    for (int n = 0; n < 4; n++) bfv[n] = *(const s8v*)&Ws[wn + n * 16 + fr][kg * 8];
#pragma unroll
    for (int m = 0; m < 4; m++)
#pragma unroll
      for (int n = 0; n < 4; n++)
        acc[m][n] = __builtin_amdgcn_mfma_f32_16x16x32_bf16(af[m], bfv[n], acc[m][n], 0, 0, 0);
  }
  int rbase = bm + wm + kg * 4;
#pragma unroll
  for (int n = 0; n < 4; n++) {
    int col = bn + wn + n * 16 + fr;
    if (col >= N) continue;
    float bv = bias ? bias[col] : 0.0f;
    if (Vt != nullptr && col >= 1024) {
      int hh = (col - 1024) >> 6, dd = (col - 1024) & 63;
#pragma unroll
      for (int m = 0; m < 4; m++) {
        int row0 = rbase + m * 16;
        int bb = row0 >> 10, ll = row0 & 1023;
        short4 pk;
        pk.x = f2bf(acc[m][n][0] + bv);
        pk.y = f2bf(acc[m][n][1] + bv);
        pk.z = f2bf(acc[m][n][2] + bv);
        pk.w = f2bf(acc[m][n][3] + bv);
        *(short4*)&Vt[((((size_t)bb * NH + hh) * DH + dd) << 10) | ll] = pk;
      }
      continue;
    }
#pragma unroll
    for (int m = 0; m < 4; m++) {
#pragma unroll
      for (int r = 0; r < 4; r++) {
        int row = rbase + m * 16 + r;
        float v = act_apply(acc[m][n][r] + bv, act);
        if (OUTBF) Cb[(size_t)row * N + col] = f2bf(v);
        else C[(size_t)row * N + col] = v;
      }
    }
  }
}

// ---------------- MFMA flash attention (V pre-transposed, reg-prefetched K/V) ----------------
__global__ __launch_bounds__(256) void mha_kernel(
    const short* __restrict__ qkv, const short* __restrict__ vt,
    const float* __restrict__ phase, short* __restrict__ out) {
  __shared__ short sQ[64][72];
  __shared__ short sK[64][72];
  __shared__ short sVt[64][72];
  __shared__ short sP[64][72];
  __shared__ float sPh[Lseq];
  int bh = blockIdx.y;
  int b = bh >> 3, h = bh & 7;
  int q0 = blockIdx.x * 64;
  int tid = threadIdx.x;
  int lane = tid & 63, wid = tid >> 6;
  int fr = lane & 15, kg = lane >> 4;
  int wm = wid * 16;
  const short* vtb = vt + ((size_t)bh * DH) * Lseq;

  int srow0 = tid >> 3, srow1 = (tid + 256) >> 3;
  int sc8_0 = (tid & 7) * 8, sc8_1 = sc8_0;
  const short* kbase = qkv + ((size_t)(b * Lseq) * 3 + 1) * D + h * DH;

  for (int j = tid; j < Lseq; j += 256) sPh[j] = phase[((size_t)(b * Lseq + j)) * NH + h];
  for (int idx = tid; idx < 512; idx += 256) {
    int row = idx >> 3, c8 = (idx & 7) * 8;
    *(s8v*)&sQ[row][c8] =
        *(const s8v*)(qkv + (((size_t)(b * Lseq + q0 + row)) * 3 + 0) * D + h * DH + c8);
  }

  s8v kr0, kr1, vr0, vr1;
  auto loadkv = [&](int k0) {
    kr0 = *(const s8v*)(kbase + (size_t)(k0 + srow0) * 3 * D + sc8_0);
    kr1 = *(const s8v*)(kbase + (size_t)(k0 + srow1) * 3 * D + sc8_1);
    vr0 = *(const s8v*)(vtb + (size_t)srow0 * Lseq + k0 + sc8_0);
    vr1 = *(const s8v*)(vtb + (size_t)srow1 * Lseq + k0 + sc8_1);
  };
  loadkv(0);
  __syncthreads();

  float phq[4];
#pragma unroll
  for (int r = 0; r < 4; r++) phq[r] = sPh[q0 + wm + kg * 4 + r];

  float mrow[4] = {-1e30f, -1e30f, -1e30f, -1e30f};
  float lrow[4] = {0.f, 0.f, 0.f, 0.f};
  f32x4 o[4] = {};

  for (int kt = 0; kt < Lseq / 64; kt++) {
    int k0 = kt * 64;
    __syncthreads();
    *(s8v*)&sK[srow0][sc8_0] = kr0;
    *(s8v*)&sK[srow1][sc8_1] = kr1;
    *(s8v*)&sVt[srow0][sc8_0] = vr0;
    *(s8v*)&sVt[srow1][sc8_1] = vr1;
    __syncthreads();
    if (kt + 1 < Lseq / 64) loadkv(k0 + 64);

    s8v qa0 = *(const s8v*)&sQ[wm + fr][kg * 8];
    s8v qa1 = *(const s8v*)&sQ[wm + fr][32 + kg * 8];
    f32x4 sacc[4];
#pragma unroll
    for (int n = 0; n < 4; n++) {
      f32x4 z = {};
      s8v kb0 = *(const s8v*)&sK[n * 16 + fr][kg * 8];
      s8v kb1 = *(const s8v*)&sK[n * 16 + fr][32 + kg * 8];
      z = __builtin_amdgcn_mfma_f32_16x16x32_bf16(qa0, kb0, z, 0, 0, 0);
      z = __builtin_amdgcn_mfma_f32_16x16x32_bf16(qa1, kb1, z, 0, 0, 0);
      sacc[n] = z;
    }
    float sv[4][4];
#pragma unroll
    for (int n = 0; n < 4; n++) {
      float phk = sPh[k0 + n * 16 + fr];
#pragma unroll
      for (int r = 0; r < 4; r++) {
        float dp = phq[r] - phk;
        sv[n][r] = sacc[n][r] * 0.125f - dp * dp;
      }
    }
    float mnew[4], alpha[4];
#pragma unroll
    for (int r = 0; r < 4; r++) {
      float mx = fmaxf(fmaxf(sv[0][r], sv[1][r]), fmaxf(sv[2][r], sv[3][r]));
#pragma unroll
      for (int off = 1; off < 16; off <<= 1) mx = fmaxf(mx, __shfl_xor(mx, off, 64));
      mnew[r] = fmaxf(mrow[r], mx);
      alpha[r] = __expf(mrow[r] - mnew[r]);
      mrow[r] = mnew[r];
    }
    float rs[4] = {0.f, 0.f, 0.f, 0.f};
#pragma unroll
    for (int n = 0; n < 4; n++) {
#pragma unroll
      for (int r = 0; r < 4; r++) {
        float p = __expf(sv[n][r] - mnew[r]);
        rs[r] += p;
        sP[wm + kg * 4 + r][n * 16 + fr] = f2bf(p);
      }
    }
#pragma unroll
    for (int r = 0; r < 4; r++) {
#pragma unroll
      for (int off = 1; off < 16; off <<= 1) rs[r] += __shfl_xor(rs[r], off, 64);
      lrow[r] = lrow[r] * alpha[r] + rs[r];
    }
#pragma unroll
    for (int df = 0; df < 4; df++) {
      o[df][0] *= alpha[0]; o[df][1] *= alpha[1];
      o[df][2] *= alpha[2]; o[df][3] *= alpha[3];
    }
    s8v pa0 = *(const s8v*)&sP[wm + fr][kg * 8];
    s8v pa1 = *(const s8v*)&sP[wm + fr][32 + kg * 8];
#pragma unroll
    for (int df = 0; df < 4; df++) {
      int d = df * 16 + fr;
      s8v vb0 = *(const s8v*)&sVt[d][kg * 8];
      s8v vb1 = *(const s8v*)&sVt[d][32 + kg * 8];
      o[df] = __builtin_amdgcn_mfma_f32_16x16x32_bf16(pa0, vb0, o[df], 0, 0, 0);
      o[df] = __builtin_amdgcn_mfma_f32_16x16x32_bf16(pa1, vb1, o[df], 0, 0, 0);
    }
  }
  float inv[4];
#pragma unroll
  for (int r = 0; r < 4; r++) inv[r] = 1.0f / lrow[r];
#pragma unroll
  for (int df = 0; df < 4; df++) {
#pragma unroll
    for (int r = 0; r < 4; r++) {
      int row = q0 + wm + kg * 4 + r;
      out[((size_t)(b * Lseq + row)) * D + h * DH + df * 16 + fr] = f2bf(o[df][r] * inv[r]);
    }
  }
}

// ---------------- fused boundary gate + xg = bf16(x * gate) ----------------
__global__ __launch_bounds__(128) void gatexg_kernel(
    const float* __restrict__ tb, const float* __restrict__ w2,
    const float* __restrict__ b2, const float* __restrict__ x,
    float* __restrict__ gate, short* __restrict__ xg) {
  __shared__ float sred[2];
  int tok = blockIdx.x, t = threadIdx.x;
  const float* row = tb + (size_t)tok * D;
  float acc = row[t] * w2[t] + row[t + 128] * w2[t + 128] +
              row[t + 256] * w2[t + 256] + row[t + 384] * w2[t + 384];
#pragma unroll
  for (int off = 32; off > 0; off >>= 1) acc += __shfl_xor(acc, off, 64);
  if ((t & 63) == 0) sred[t >> 6] = acc;
  __syncthreads();
  float g = 1.0f / (1.0f + expf(-(sred[0] + sred[1] + b2[0])));
  if (t == 0) gate[tok] = g;
  float4 v = *(const float4*)(x + (size_t)tok * D + t * 4);
  short4 o = make_short4(f2bf(v.x * g), f2bf(v.y * g), f2bf(v.z * g), f2bf(v.w * g));
  *(short4*)(xg + (size_t)tok * D + t * 4) = o;
}

extern "C" void kernel_launch(void* const* d_in, const int* in_sizes, int n_in,
                              void* d_out, int out_size, void* d_ws, size_t ws_size,
                              hipStream_t stream) {
  const int* ids = (const int*)d_in[0];
  const float* emb = (const float*)d_in[1];
  const float* pos = (const float*)d_in[2];
  const float* rg_w = (const float*)d_in[3];
  const float* rg_b = (const float*)d_in[4];
  const float* qkv_w = (const float*)d_in[5];
  const float* qkv_b = (const float*)d_in[6];
  const float* out_w = (const float*)d_in[7];
  const float* out_b = (const float*)d_in[8];
  const float* ph_w = (const float*)d_in[9];
  const float* ph_b = (const float*)d_in[10];
  const float* ff1_w = (const float*)d_in[11];
  const float* ff1_b = (const float*)d_in[12];
  const float* ff2_w = (const float*)d_in[13];
  const float* ff2_b = (const float*)d_in[14];
  const float* n1_s = (const float*)d_in[15];
  const float* n1_b = (const float*)d_in[16];
  const float* n2_s = (const float*)d_in[17];
  const float* n2_b = (const float*)d_in[18];
  const float* bw1 = (const float*)d_in[19];
  const float* bb1 = (const float*)d_in[20];
  const float* bw2 = (const float*)d_in[21];
  const float* bb2 = (const float*)d_in[22];
  const float* head_w = (const float*)d_in[23];

  char* w = (char*)d_ws;
  float* x      = (float*)(w + 0);           //  8.39 MB
  float* ao     = (float*)(w + 8388608);     //  8.39 MB (bnd tanh-buf; first 4.2 MB doubles as y_bf)
  short* y_bf   = (short*)(w + 8388608);     //  4.19 MB (residual-add input, bf16)
  float* phase  = (float*)(w + 16777216);    //  0.13 MB
  short* h_bf   = (short*)(w + 16908288);    //  4.19 MB
  short* ao_bf  = (short*)(w + 21102592);    //  4.19 MB
  short* x_bf   = (short*)(w + 25296896);    //  4.19 MB
  short* ff_bf  = (short*)(w + 29491200);    // 16.78 MB
  short* xg_bf  = (short*)(w + 46268416);    //  4.19 MB
  short* qkv_bf = (short*)(w + 50462720);    // 12.58 MB
  short* vt_bf  = (short*)(w + 63045632);    //  4.19 MB
  short* wqkv   = (short*)(w + 67239936);    //  9.44 MB
  short* wout   = (short*)(w + 76677120);    //  3.15 MB
  short* wff1   = (short*)(w + 79822848);    // 12.58 MB
  short* wff2   = (short*)(w + 92405760);    // 12.58 MB
  short* wbnd   = (short*)(w + 104988672);   //  0.52 MB
  short* whead  = (short*)(w + 105512960);   // 30.72 MB
  const size_t WS_FULL = 136232960;

  float* outf   = (float*)d_out;
  float* logits = outf;
  float* gate   = outf + 122880000;
  float* rg_out = outf + 122884096;

  bool fast = ws_size >= WS_FULL;

  if (fast) {
    f2bf6_kernel<<<(34496512 / 8 + 255) / 256, 256, 0, stream>>>(
        qkv_w, wqkv, 4718592, out_w, wout, 1572864, ff1_w, wff1, 6291456,
        ff2_w, wff2, 6291456, bw1, wbnd, 262144, head_w, whead, 15360000);
  }

  embed_kernel<<<BL, 128, 0, stream>>>(ids, emb, pos, x);
  rg_ln_kernel<<<BL, 256, 0, stream>>>(
      x, rg_w, rg_b, n1_s, n1_b, ph_w, ph_b,
      h_bf, phase, (NL == 1) ? rg_out : nullptr);

  for (int l = 0; l < NL; l++) {
    if (fast)
      gemm64_kernel<true><<<dim3(12, 64), 256, 0, stream>>>(
          h_bf, wqkv + (size_t)l * 1536 * D, qkv_b + l * 1536, nullptr, qkv_bf, vt_bf,
          BL, 1536, D, 0);
    else
      gemm_conv_kernel<true><<<dim3(12, 32), 256, 0, stream>>>(
          h_bf, qkv_w + (size_t)l * 1536 * D, qkv_b + l * 1536, nullptr, qkv_bf, vt_bf,
          BL, 1536, D, 0);
    mha_kernel<<<dim3(Lseq / 64, Bsz * NH), 256, 0, stream>>>(qkv_bf, vt_bf, phase, ao_bf);
    if (fast)
      gemm64_kernel<true><<<dim3(4, 64), 256, 0, stream>>>(
          ao_bf, wout + (size_t)l * D * D, out_b + l * D, nullptr, y_bf, nullptr, BL, D, D, 0);
    else
      gemm_conv_kernel<true><<<dim3(4, 32), 256, 0, stream>>>(
          ao_bf, out_w + (size_t)l * D * D, out_b + l * D, nullptr, y_bf, nullptr, BL, D, D, 0);
    residual_ln_kernel<<<BL, 256, 0, stream>>>(x, y_bf, n1_s + l * D, n1_b + l * D, x_bf);
    if (fast)
      gemm64_kernel<true><<<dim3(16, 64), 256, 0, stream>>>(
          x_bf, wff1 + (size_t)l * 2048 * D, ff1_b + l * 2048, nullptr, ff_bf, nullptr,
          BL, 2048, D, 1);
    else
      gemm_conv_kernel<true><<<dim3(16, 32), 256, 0, stream>>>(
          x_bf, ff1_w + (size_t)l * 2048 * D, ff1_b + l * 2048, nullptr, ff_bf, nullptr,
          BL, 2048, D, 1);
    if (fast)
      gemm64_kernel<true><<<dim3(4, 64), 256, 0, stream>>>(
          ff_bf, wff2 + (size_t)l * D * 2048, ff2_b + l * D, nullptr, y_bf, nullptr,
          BL, D, 2048, 0);
    else
      gemm_conv_kernel<true><<<dim3(4, 32), 256, 0, stream>>>(
          ff_bf, ff2_w + (size_t)l * D * 2048, ff2_b + l * D, nullptr, y_bf, nullptr,
          BL, D, 2048, 0);
    if (l < NL - 1) {
      // fused: residual+LN2 of layer l, then rg/LN1/phase of layer l+1
      resrg_kernel<<<BL, 256, 0, stream>>>(
          x, y_bf, n2_s + l * D, n2_b + l * D,
          rg_w + (size_t)(l + 1) * 4 * D, rg_b + (l + 1) * 4,
          n1_s + (l + 1) * D, n1_b + (l + 1) * D,
          ph_w + (size_t)(l + 1) * NH * D, ph_b + (l + 1) * NH,
          h_bf, phase, (l + 1 == NL - 1) ? rg_out : nullptr);
    } else {
      residual_ln_kernel<<<BL, 256, 0, stream>>>(x, y_bf, n2_s + l * D, n2_b + l * D, x_bf);
    }
  }

  if (fast)
    gemm64_kernel<false><<<dim3(4, 64), 256, 0, stream>>>(
        x_bf, wbnd, bb1, ao, nullptr, nullptr, BL, D, D, 2);
  else
    gemm_conv_kernel<false><<<dim3(4, 32), 256, 0, stream>>>(
        x_bf, bw1, bb1, ao, nullptr, nullptr, BL, D, D, 2);
  gatexg_kernel<<<BL, 128, 0, stream>>>(ao, bw2, bb2, x, gate, xg_bf);
  if (fast)
    gemm128_kernel<1, true><<<dim3(32, 235), 256, 0, stream>>>(
        xg_bf, whead, nullptr, logits, BL, Vocab, D, 0);
  else
    gemm_conv_kernel<false><<<dim3(235, 32), 256, 0, stream>>>(
        xg_bf, head_w, nullptr, logits, nullptr, nullptr, BL, Vocab, D, 0);
}